// Round 7
// baseline (233.268 us; speedup 1.0000x reference)
//
#include <hip/hip_runtime.h>
#include <math.h>

#define NPTS 4096
#define NBATCH 8

// ws layout (float offsets)
#define WS_SRC    0          // [8][3][4096]                 = 98304
#define WS_PACKED 98304      // [8][4096] float4             = 131072 floats
#define WS_PART   229376     // 2 x [512][16] ping-pong      = 16384 floats
#define WS_FPART  229376     // overlaps PART slot0 (dead by k_final)
#define WS_STATE  245760     // slot0 {prev_err,done} slot1 {prev_err,done}

__device__ __forceinline__ void jrot(double A[3][3], double V[3][3], int p, int q) {
  double apq = A[p][q];
  if (fabs(apq) > 0.0) {
    double tau = (A[q][q] - A[p][p]) / (2.0 * apq);
    double tt = (tau >= 0.0 ? 1.0 : -1.0) / (fabs(tau) + sqrt(1.0 + tau * tau));
    double c = 1.0 / sqrt(1.0 + tt * tt);
    double s = tt * c;
#pragma unroll
    for (int k = 0; k < 3; ++k) { double akp = A[k][p], akq = A[k][q]; A[k][p] = c*akp - s*akq; A[k][q] = s*akp + c*akq; }
#pragma unroll
    for (int k = 0; k < 3; ++k) { double apk = A[p][k], aqk = A[q][k]; A[p][k] = c*apk - s*aqk; A[q][k] = s*apk + c*aqk; }
#pragma unroll
    for (int k = 0; k < 3; ++k) { double vkp = V[k][p], vkq = V[k][q]; V[k][p] = c*vkp - s*vkq; V[k][q] = s*vkp + c*vkq; }
  }
}

// P = sum s_i c_j (row-major 9), Ss = sum s, Sc = sum c, n = 4096.
// Kabsch R (src->corr), t = cbar - R sbar; matches svd+reflection-fix reference.
__device__ void kabsch3(const double P[9], const double Ss[3], const double Sc[3],
                        double R[3][3], double t[3]) {
  const double invn = 1.0 / 4096.0;
  double sb[3], cb[3];
#pragma unroll
  for (int i = 0; i < 3; ++i) { sb[i] = Ss[i] * invn; cb[i] = Sc[i] * invn; }
  double H[3][3];
#pragma unroll
  for (int i = 0; i < 3; ++i)
#pragma unroll
    for (int j = 0; j < 3; ++j)
      H[i][j] = P[i * 3 + j] - Ss[i] * cb[j];

  double A[3][3];
  double V[3][3] = {{1,0,0},{0,1,0},{0,0,1}};
#pragma unroll
  for (int i = 0; i < 3; ++i)
#pragma unroll
    for (int j = 0; j < 3; ++j)
      A[i][j] = H[0][i]*H[0][j] + H[1][i]*H[1][j] + H[2][i]*H[2][j];

  for (int sw = 0; sw < 6; ++sw) {
    jrot(A, V, 0, 1);
    jrot(A, V, 0, 2);
    jrot(A, V, 1, 2);
  }
  double l0 = A[0][0], l1 = A[1][1], l2 = A[2][2];
  if (l0 < l1) {
    double tm = l0; l0 = l1; l1 = tm;
#pragma unroll
    for (int k = 0; k < 3; ++k) { double tv = V[k][0]; V[k][0] = V[k][1]; V[k][1] = tv; }
  }
  if (l0 < l2) {
    double tm = l0; l0 = l2; l2 = tm;
#pragma unroll
    for (int k = 0; k < 3; ++k) { double tv = V[k][0]; V[k][0] = V[k][2]; V[k][2] = tv; }
  }
  if (l1 < l2) {
    double tm = l1; l1 = l2; l2 = tm;
#pragma unroll
    for (int k = 0; k < 3; ++k) { double tv = V[k][1]; V[k][1] = V[k][2]; V[k][2] = tv; }
  }
  double U[3][3];
  double nrm0 = 0.0, nrm2 = 0.0;
#pragma unroll
  for (int k = 0; k < 3; ++k) {
    double ux = H[0][0]*V[0][k] + H[0][1]*V[1][k] + H[0][2]*V[2][k];
    double uy = H[1][0]*V[0][k] + H[1][1]*V[1][k] + H[1][2]*V[2][k];
    double uz = H[2][0]*V[0][k] + H[2][1]*V[1][k] + H[2][2]*V[2][k];
    double nn2 = sqrt(ux*ux + uy*uy + uz*uz);
    if (k == 0) nrm0 = nn2;
    if (k == 2) nrm2 = nn2;
    double inv = (nn2 > 0.0) ? 1.0 / nn2 : 0.0;
    U[0][k] = ux * inv; U[1][k] = uy * inv; U[2][k] = uz * inv;
  }
  if (nrm0 <= 1e-30) {
#pragma unroll
    for (int i = 0; i < 3; ++i)
#pragma unroll
      for (int j = 0; j < 3; ++j)
        R[i][j] = (i == j) ? 1.0 : 0.0;
  } else {
    if (nrm2 <= nrm0 * 1e-12) {
      double cx = U[1][0]*U[2][1] - U[2][0]*U[1][1];
      double cy = U[2][0]*U[0][1] - U[0][0]*U[2][1];
      double cz = U[0][0]*U[1][1] - U[1][0]*U[0][1];
      double cn = sqrt(cx*cx + cy*cy + cz*cz);
      double inv = (cn > 0.0) ? 1.0 / cn : 0.0;
      U[0][2] = cx * inv; U[1][2] = cy * inv; U[2][2] = cz * inv;
    }
#pragma unroll
    for (int i = 0; i < 3; ++i)
#pragma unroll
      for (int j = 0; j < 3; ++j)
        R[i][j] = V[i][0]*U[j][0] + V[i][1]*U[j][1] + V[i][2]*U[j][2];
    double det =
        R[0][0]*(R[1][1]*R[2][2] - R[1][2]*R[2][1])
      - R[0][1]*(R[1][0]*R[2][2] - R[1][2]*R[2][0])
      + R[0][2]*(R[1][0]*R[2][1] - R[1][1]*R[2][0]);
    if (det < 0.0) {
#pragma unroll
      for (int i = 0; i < 3; ++i)
#pragma unroll
        for (int j = 0; j < 3; ++j)
          R[i][j] -= 2.0 * V[i][2] * U[j][2];
    }
  }
#pragma unroll
  for (int i = 0; i < 3; ++i)
    t[i] = cb[i] - (R[i][0]*sb[0] + R[i][1]*sb[1] + R[i][2]*sb[2]);
}

// Block-redundant solve helper: reduce partials (512 rows x 16) for all 8
// batches, run Kabsch on lane j==0 of each 32-thread group, publish R,t to
// s_RT and the scalar err sum to s_val. Requires blockDim >= 256.
// Caller must __syncthreads() after.
__device__ __forceinline__ void solve_head(const float* __restrict__ PT,
                                           float s_RT[8][12], float s_val[8],
                                           int tid) {
  if (tid < 256) {
    const int sb2 = tid >> 5;
    const int j = tid & 31;
    float acc[16];
    const float* P0 = PT + ((sb2 << 6) + j) * 16;
    const float* P1 = P0 + 32 * 16;
#pragma unroll
    for (int k = 0; k < 16; ++k) acc[k] = P0[k] + P1[k];
#pragma unroll
    for (int k = 0; k < 16; ++k) {
      float v = acc[k];
      v += __shfl_xor(v, 16, 64);
      v += __shfl_xor(v, 8, 64);
      v += __shfl_xor(v, 4, 64);
      v += __shfl_xor(v, 2, 64);
      v += __shfl_xor(v, 1, 64);
      acc[k] = v;
    }
    if (j == 0) {
      s_val[sb2] = acc[0];
      double Ss[3] = {acc[1], acc[2], acc[3]};
      double Sc[3] = {acc[4], acc[5], acc[6]};
      double Pm[9];
#pragma unroll
      for (int k = 0; k < 9; ++k) Pm[k] = acc[7 + k];
      double R[3][3], tr[3];
      kabsch3(Pm, Ss, Sc, R, tr);
#pragma unroll
      for (int i = 0; i < 3; ++i)
#pragma unroll
        for (int jj = 0; jj < 3; ++jj) s_RT[sb2][i * 3 + jj] = (float)R[i][jj];
#pragma unroll
      for (int i = 0; i < 3; ++i) s_RT[sb2][9 + i] = (float)tr[i];
    }
  }
}

__global__ void k_prep(const float* __restrict__ srcInit, const float* __restrict__ dst,
                       float* __restrict__ ws, float* __restrict__ out) {
  const int gid = blockIdx.x * blockDim.x + threadIdx.x;
  const int stride = gridDim.x * blockDim.x;
  float4* packed = (float4*)(ws + WS_PACKED);
  for (int i = gid; i < NBATCH * NPTS; i += stride) {
    const int b = i >> 12, m = i & (NPTS - 1);
    const float dx = dst[b * 3 * NPTS + m];
    const float dy = dst[b * 3 * NPTS + NPTS + m];
    const float dz = dst[b * 3 * NPTS + 2 * NPTS + m];
    const float nyy = -fmaf(dx, dx, fmaf(dy, dy, dz * dz));
    packed[i] = make_float4(dx, dy, dz, nyy);
  }
  const float4* s4 = (const float4*)srcInit;
  float4* w4 = (float4*)(ws + WS_SRC);
  float4* o4 = (float4*)out;
  for (int i = gid; i < (NBATCH * 3 * NPTS) / 4; i += stride) {
    float4 v = s4[i];
    w4[i] = v;
    o4[i] = v;  // output 0: srcInit pass-through
  }
  if (gid == 0) {
    ws[WS_STATE + 0] = 0.0f;  // slot0 prev_err (= err_{-1})
    ws[WS_STATE + 1] = 0.0f;  // slot0 done_{-1}
  }
}

// 8 float4 group buffer held in named registers (all accesses static).
struct G8 { float4 v0, v1, v2, v3, v4, v5, v6, v7; };

// Load group gidx (8 consecutive float4 of this wave's slice). Clamp keeps
// trailing pipeline loads in-bounds (values unused).
__device__ __forceinline__ void loadg(G8& r, const float4* __restrict__ bp, int gidx) {
  const int g = gidx > 63 ? 63 : gidx;
  const float4* __restrict__ p = bp + (g << 3);
  r.v0 = p[0]; r.v1 = p[1]; r.v2 = p[2]; r.v3 = p[3];
  r.v4 = p[4]; r.v5 = p[5]; r.v6 = p[6]; r.v7 = p[7];
}

// Evaluate group: 24 fma + max3-friendly tree + group-winner update.
__device__ __forceinline__ void compg(const G8& r, float s2x, float s2y, float s2z,
                                      float& best, int& gwin, int gidx) {
  const float p0 = fmaf(s2x, r.v0.x, fmaf(s2y, r.v0.y, fmaf(s2z, r.v0.z, r.v0.w)));
  const float p1 = fmaf(s2x, r.v1.x, fmaf(s2y, r.v1.y, fmaf(s2z, r.v1.z, r.v1.w)));
  const float p2 = fmaf(s2x, r.v2.x, fmaf(s2y, r.v2.y, fmaf(s2z, r.v2.z, r.v2.w)));
  const float p3 = fmaf(s2x, r.v3.x, fmaf(s2y, r.v3.y, fmaf(s2z, r.v3.z, r.v3.w)));
  const float p4 = fmaf(s2x, r.v4.x, fmaf(s2y, r.v4.y, fmaf(s2z, r.v4.z, r.v4.w)));
  const float p5 = fmaf(s2x, r.v5.x, fmaf(s2y, r.v5.y, fmaf(s2z, r.v5.z, r.v5.w)));
  const float p6 = fmaf(s2x, r.v6.x, fmaf(s2y, r.v6.y, fmaf(s2z, r.v6.z, r.v6.w)));
  const float p7 = fmaf(s2x, r.v7.x, fmaf(s2y, r.v7.y, fmaf(s2z, r.v7.z, r.v7.w)));
  const float t0 = fmaxf(fmaxf(p0, p1), p2);
  const float t1 = fmaxf(fmaxf(p3, p4), p5);
  const float t2 = fmaxf(p6, p7);
  const float gm = fmaxf(fmaxf(t0, t1), t2);
  if (gm > best) { best = gm; gwin = gidx; }  // strict >: first-max kept
}

// grid (64,8) x 512 thr, launched 10x with it=0..9.
// Dispatch it: [it>0] block-redundant solve of fit_{it-1} from partials
// slot (it-1)&1, apply R,t, then NN scan writing partials slot it&1.
// Inner scan: 4-buffer software pipeline, prefetch distance 3 groups
// (24 loads in flight ~ L2 latency), max3 reduction tree.
__global__ void __launch_bounds__(512, 2) k_nn(float* __restrict__ ws, int it) {
  const int b = blockIdx.y;
  const int chunk = blockIdx.x;
  const int tid = threadIdx.x;
  const int slice = tid >> 6;
  const int pidx = tid & 63;
  const int n = (chunk << 6) + pidx;

  __shared__ float rv[8][64];
  __shared__ int ri[8][64];
  __shared__ float s_RT[8][12];
  __shared__ float s_val[8];
  __shared__ float s_done_new;

  float* state = ws + WS_STATE;
  float* src = ws + WS_SRC;
  const int sbase = b * 3 * NPTS + n;
  float sx = src[sbase];
  float sy = src[sbase + NPTS];
  float sz = src[sbase + 2 * NPTS];

  bool skip_scan = false;
  if (it > 0) {
    const int ps = (it - 1) & 1;
    const float prev_err = state[ps * 2 + 0];   // err_{it-2}
    const float done_prev = state[ps * 2 + 1];  // done_{it-2}
    if (done_prev != 0.0f) {
      // fully frozen: copy state forward, touch nothing else
      if (blockIdx.x == 0 && blockIdx.y == 0 && tid == 0) {
        state[(it & 1) * 2 + 0] = prev_err;
        state[(it & 1) * 2 + 1] = 1.0f;
      }
      return;
    }
    // block-redundant solve of fit_{it-1}
    solve_head(ws + WS_PART + ps * 8192, s_RT, s_val, tid);
    __syncthreads();  // publish s_RT/s_val; also: all src reads above done
    if (tid == 0) {
      float total = 0.0f;
#pragma unroll
      for (int bb = 0; bb < 8; ++bb) total += s_val[bb];
      const float err = total * (1.0f / 32768.0f);  // err_{it-1}
      const float dn = (fabsf(prev_err - err) < 0.001f) ? 1.0f : 0.0f;
      s_done_new = dn;
      if (blockIdx.x == 0 && blockIdx.y == 0) {
        state[(it & 1) * 2 + 0] = err;
        state[(it & 1) * 2 + 1] = dn;
      }
    }
    __syncthreads();  // publish s_done_new
    // apply R_{it-1},t (done_{it-2}==0 here)
    const float* RT = s_RT[b];
    const float nx = fmaf(RT[0], sx, fmaf(RT[1], sy, fmaf(RT[2], sz, RT[9])));
    const float ny = fmaf(RT[3], sx, fmaf(RT[4], sy, fmaf(RT[5], sz, RT[10])));
    const float nz = fmaf(RT[6], sx, fmaf(RT[7], sy, fmaf(RT[8], sz, RT[11])));
    sx = nx; sy = ny; sz = nz;
    if (slice == 0) {  // safe: all reads completed before first barrier
      src[sbase] = sx;
      src[sbase + NPTS] = sy;
      src[sbase + 2 * NPTS] = sz;
    }
    skip_scan = (s_done_new != 0.0f);
  }

  if (skip_scan) return;  // uniform across grid

  const float4* __restrict__ packed = ((const float4*)(ws + WS_PACKED)) + b * NPTS;
  const float s2x = 2.0f * sx, s2y = 2.0f * sy, s2z = 2.0f * sz;
  const int m0 = slice << 9;
  const float4* __restrict__ bp = packed + m0;

  float best = -3.0e38f;
  int gwin = 0;

  G8 ga, gb_, gc, gd;
  loadg(ga, bp, 0);
  loadg(gb_, bp, 1);
  loadg(gc, bp, 2);
#pragma unroll 1
  for (int g = 0; g < 64; g += 4) {
    loadg(gd, bp, g + 3);  compg(ga, s2x, s2y, s2z, best, gwin, g);
    loadg(ga, bp, g + 4);  compg(gb_, s2x, s2y, s2z, best, gwin, g + 1);
    loadg(gb_, bp, g + 5); compg(gc, s2x, s2y, s2z, best, gwin, g + 2);
    loadg(gc, bp, g + 6);  compg(gd, s2x, s2y, s2z, best, gwin, g + 3);
  }

  // Exact first-max index within winning group (bit-identical recompute,
  // descending j so smallest index wins).
  const int gbase = m0 + (gwin << 3);
  const float4* __restrict__ gp = packed + gbase;
  int bi = gbase;
#pragma unroll
  for (int j = 7; j >= 0; --j) {
    const float4 d = gp[j];
    const float p = fmaf(s2x, d.x, fmaf(s2y, d.y, fmaf(s2z, d.z, d.w)));
    if (p == best) bi = gbase + j;
  }

  rv[slice][pidx] = best;
  ri[slice][pidx] = bi;
  __syncthreads();

  if (slice == 0) {
    float bv = rv[0][pidx];
    int bidx = ri[0][pidx];
#pragma unroll
    for (int s = 1; s < 8; ++s) {
      const float v = rv[s][pidx];
      if (v > bv) { bv = v; bidx = ri[s][pidx]; }  // ascending slice: first max
    }
    const float4 c = packed[bidx];
    const float xx = fmaf(sx, sx, fmaf(sy, sy, sz * sz));
    float vals[16];
    vals[0] = bv - xx;          // val = max(2 s.d - yy) - xx
    vals[1] = sx;  vals[2] = sy;  vals[3] = sz;
    vals[4] = c.x; vals[5] = c.y; vals[6] = c.z;
    vals[7]  = sx * c.x; vals[8]  = sx * c.y; vals[9]  = sx * c.z;
    vals[10] = sy * c.x; vals[11] = sy * c.y; vals[12] = sy * c.z;
    vals[13] = sz * c.x; vals[14] = sz * c.y; vals[15] = sz * c.z;
#pragma unroll
    for (int k = 0; k < 16; ++k) {
      float v = vals[k];
#pragma unroll
      for (int off = 32; off >= 1; off >>= 1) v += __shfl_xor(v, off, 64);
      vals[k] = v;
    }
    if (pidx == 0) {
      float* Pp = ws + WS_PART + (it & 1) * 8192 + ((b << 6) + chunk) * 16;
#pragma unroll
      for (int k = 0; k < 16; ++k) Pp[k] = vals[k];
    }
  }
}

// grid (16,8) x 256 thr (= dispatch 10): block-redundant solve of fit_9 from
// partials slot 1 (gated on done_8 in state slot 1), apply, write final src,
// emit partials for the final Kabsch.
__global__ void __launch_bounds__(256, 4) k_final(const float* __restrict__ srcInit,
                                                  float* __restrict__ ws,
                                                  float* __restrict__ out) {
  const int b = blockIdx.y;
  const int chunk = blockIdx.x;
  const int tid = threadIdx.x;
  const int n = (chunk << 8) + tid;
  __shared__ float red[4][15];
  __shared__ float s_RT[8][12];
  __shared__ float s_val[8];
  float* state = ws + WS_STATE;
  const float done8 = state[2 + 1];  // slot1.done (written by dispatch it=9)
  const int sbase = b * 3 * NPTS + n;
  float sx = ws[WS_SRC + sbase];
  float sy = ws[WS_SRC + sbase + NPTS];
  float sz = ws[WS_SRC + sbase + 2 * NPTS];
  if (done8 == 0.0f) {
    solve_head(ws + WS_PART + 8192, s_RT, s_val, tid);  // fit_9 from slot1
    __syncthreads();
    const float* RT = s_RT[b];
    const float nx = fmaf(RT[0], sx, fmaf(RT[1], sy, fmaf(RT[2], sz, RT[9])));
    const float ny = fmaf(RT[3], sx, fmaf(RT[4], sy, fmaf(RT[5], sz, RT[10])));
    const float nz = fmaf(RT[6], sx, fmaf(RT[7], sy, fmaf(RT[8], sz, RT[11])));
    sx = nx; sy = ny; sz = nz;
  }
  out[98304 + sbase] = sx;
  out[98304 + sbase + NPTS] = sy;
  out[98304 + sbase + 2 * NPTS] = sz;

  const float ax = srcInit[sbase];
  const float ay = srcInit[sbase + NPTS];
  const float az = srcInit[sbase + 2 * NPTS];
  float vals[15];
  vals[0] = ax; vals[1] = ay; vals[2] = az;
  vals[3] = sx; vals[4] = sy; vals[5] = sz;
  vals[6]  = ax * sx; vals[7]  = ax * sy; vals[8]  = ax * sz;
  vals[9]  = ay * sx; vals[10] = ay * sy; vals[11] = ay * sz;
  vals[12] = az * sx; vals[13] = az * sy; vals[14] = az * sz;
  const int w = tid >> 6, lane = tid & 63;
#pragma unroll
  for (int k = 0; k < 15; ++k) {
    float v = vals[k];
#pragma unroll
    for (int off = 32; off >= 1; off >>= 1) v += __shfl_xor(v, off, 64);
    vals[k] = v;
  }
  if (lane == 0) {
#pragma unroll
    for (int k = 0; k < 15; ++k) red[w][k] = vals[k];
  }
  __syncthreads();
  if (tid == 0) {
    float* FP = ws + WS_FPART + ((b << 4) + chunk) * 15;
#pragma unroll
    for (int k = 0; k < 15; ++k) FP[k] = red[0][k] + red[1][k] + red[2][k] + red[3][k];
  }
}

__global__ void __launch_bounds__(256) k_fsolve(float* __restrict__ ws, float* __restrict__ out) {
  const int t = threadIdx.x;
  const int b = t >> 5;
  const int j = t & 31;
  float acc[15];
  if (j < 16) {
    const float* F = ws + WS_FPART + ((b << 4) + j) * 15;
#pragma unroll
    for (int k = 0; k < 15; ++k) acc[k] = F[k];
  } else {
#pragma unroll
    for (int k = 0; k < 15; ++k) acc[k] = 0.0f;
  }
#pragma unroll
  for (int k = 0; k < 15; ++k) {
    float v = acc[k];
    v += __shfl_xor(v, 16, 64);
    v += __shfl_xor(v, 8, 64);
    v += __shfl_xor(v, 4, 64);
    v += __shfl_xor(v, 2, 64);
    v += __shfl_xor(v, 1, 64);
    acc[k] = v;
  }
  if (j == 0) {
    double Ss[3] = {acc[0], acc[1], acc[2]};
    double Sc[3] = {acc[3], acc[4], acc[5]};
    double Pm[9];
#pragma unroll
    for (int k = 0; k < 9; ++k) Pm[k] = acc[6 + k];
    double R[3][3], tr[3];
    kabsch3(Pm, Ss, Sc, R, tr);
#pragma unroll
    for (int i = 0; i < 3; ++i) {
#pragma unroll
      for (int jj = 0; jj < 3; ++jj) {
        out[196608 + b * 9 + i * 3 + jj] = (float)R[i][jj];       // rotation_ab
        out[196704 + b * 9 + i * 3 + jj] = (float)R[jj][i];       // rotation_ba = R^T
      }
      out[196680 + b * 3 + i] = (float)tr[i];                     // translation_ab
      out[196776 + b * 3 + i] =
          (float)(-(R[0][i] * tr[0] + R[1][i] * tr[1] + R[2][i] * tr[2]));  // -R^T t
    }
  }
}

extern "C" void kernel_launch(void* const* d_in, const int* in_sizes, int n_in,
                              void* d_out, int out_size, void* d_ws, size_t ws_size,
                              hipStream_t stream) {
  (void)in_sizes; (void)n_in; (void)out_size; (void)ws_size;
  const float* srcInit = (const float*)d_in[0];
  const float* dst = (const float*)d_in[1];
  float* out = (float*)d_out;
  float* ws = (float*)d_ws;

  k_prep<<<256, 256, 0, stream>>>(srcInit, dst, ws, out);
  for (int it = 0; it < 10; ++it)
    k_nn<<<dim3(64, 8), 512, 0, stream>>>(ws, it);
  k_final<<<dim3(16, 8), 256, 0, stream>>>(srcInit, ws, out);
  k_fsolve<<<1, 256, 0, stream>>>(ws, out);
}

// Round 8
// 221.090 us; speedup vs baseline: 1.0551x; 1.0551x over previous
//
#include <hip/hip_runtime.h>
#include <math.h>

#define NPTS 4096
#define NBATCH 8

// ws layout (float offsets)
#define WS_SRC    0          // [8][3][4096]                 = 98304
#define WS_PACKED 98304      // [8][4096] float4             = 131072 floats
#define WS_PART   229376     // 2 x [512][16] ping-pong      = 16384 floats
#define WS_FPART  229376     // overlaps PART slot0 (dead by k_final)
#define WS_STATE  245760     // slot0 {prev_err,done} slot1 {prev_err,done}

__device__ __forceinline__ void jrot(double A[3][3], double V[3][3], int p, int q) {
  double apq = A[p][q];
  if (fabs(apq) > 0.0) {
    double tau = (A[q][q] - A[p][p]) / (2.0 * apq);
    double tt = (tau >= 0.0 ? 1.0 : -1.0) / (fabs(tau) + sqrt(1.0 + tau * tau));
    double c = 1.0 / sqrt(1.0 + tt * tt);
    double s = tt * c;
#pragma unroll
    for (int k = 0; k < 3; ++k) { double akp = A[k][p], akq = A[k][q]; A[k][p] = c*akp - s*akq; A[k][q] = s*akp + c*akq; }
#pragma unroll
    for (int k = 0; k < 3; ++k) { double apk = A[p][k], aqk = A[q][k]; A[p][k] = c*apk - s*aqk; A[q][k] = s*apk + c*aqk; }
#pragma unroll
    for (int k = 0; k < 3; ++k) { double vkp = V[k][p], vkq = V[k][q]; V[k][p] = c*vkp - s*vkq; V[k][q] = s*vkp + c*vkq; }
  }
}

// P = sum s_i c_j (row-major 9), Ss = sum s, Sc = sum c, n = 4096.
// Kabsch R (src->corr), t = cbar - R sbar; matches svd+reflection-fix reference.
__device__ void kabsch3(const double P[9], const double Ss[3], const double Sc[3],
                        double R[3][3], double t[3]) {
  const double invn = 1.0 / 4096.0;
  double sb[3], cb[3];
#pragma unroll
  for (int i = 0; i < 3; ++i) { sb[i] = Ss[i] * invn; cb[i] = Sc[i] * invn; }
  double H[3][3];
#pragma unroll
  for (int i = 0; i < 3; ++i)
#pragma unroll
    for (int j = 0; j < 3; ++j)
      H[i][j] = P[i * 3 + j] - Ss[i] * cb[j];

  double A[3][3];
  double V[3][3] = {{1,0,0},{0,1,0},{0,0,1}};
#pragma unroll
  for (int i = 0; i < 3; ++i)
#pragma unroll
    for (int j = 0; j < 3; ++j)
      A[i][j] = H[0][i]*H[0][j] + H[1][i]*H[1][j] + H[2][i]*H[2][j];

  for (int sw = 0; sw < 6; ++sw) {
    jrot(A, V, 0, 1);
    jrot(A, V, 0, 2);
    jrot(A, V, 1, 2);
  }
  double l0 = A[0][0], l1 = A[1][1], l2 = A[2][2];
  if (l0 < l1) {
    double tm = l0; l0 = l1; l1 = tm;
#pragma unroll
    for (int k = 0; k < 3; ++k) { double tv = V[k][0]; V[k][0] = V[k][1]; V[k][1] = tv; }
  }
  if (l0 < l2) {
    double tm = l0; l0 = l2; l2 = tm;
#pragma unroll
    for (int k = 0; k < 3; ++k) { double tv = V[k][0]; V[k][0] = V[k][2]; V[k][2] = tv; }
  }
  if (l1 < l2) {
    double tm = l1; l1 = l2; l2 = tm;
#pragma unroll
    for (int k = 0; k < 3; ++k) { double tv = V[k][1]; V[k][1] = V[k][2]; V[k][2] = tv; }
  }
  double U[3][3];
  double nrm0 = 0.0, nrm2 = 0.0;
#pragma unroll
  for (int k = 0; k < 3; ++k) {
    double ux = H[0][0]*V[0][k] + H[0][1]*V[1][k] + H[0][2]*V[2][k];
    double uy = H[1][0]*V[0][k] + H[1][1]*V[1][k] + H[1][2]*V[2][k];
    double uz = H[2][0]*V[0][k] + H[2][1]*V[1][k] + H[2][2]*V[2][k];
    double nn2 = sqrt(ux*ux + uy*uy + uz*uz);
    if (k == 0) nrm0 = nn2;
    if (k == 2) nrm2 = nn2;
    double inv = (nn2 > 0.0) ? 1.0 / nn2 : 0.0;
    U[0][k] = ux * inv; U[1][k] = uy * inv; U[2][k] = uz * inv;
  }
  if (nrm0 <= 1e-30) {
#pragma unroll
    for (int i = 0; i < 3; ++i)
#pragma unroll
      for (int j = 0; j < 3; ++j)
        R[i][j] = (i == j) ? 1.0 : 0.0;
  } else {
    if (nrm2 <= nrm0 * 1e-12) {
      double cx = U[1][0]*U[2][1] - U[2][0]*U[1][1];
      double cy = U[2][0]*U[0][1] - U[0][0]*U[2][1];
      double cz = U[0][0]*U[1][1] - U[1][0]*U[0][1];
      double cn = sqrt(cx*cx + cy*cy + cz*cz);
      double inv = (cn > 0.0) ? 1.0 / cn : 0.0;
      U[0][2] = cx * inv; U[1][2] = cy * inv; U[2][2] = cz * inv;
    }
#pragma unroll
    for (int i = 0; i < 3; ++i)
#pragma unroll
      for (int j = 0; j < 3; ++j)
        R[i][j] = V[i][0]*U[j][0] + V[i][1]*U[j][1] + V[i][2]*U[j][2];
    double det =
        R[0][0]*(R[1][1]*R[2][2] - R[1][2]*R[2][1])
      - R[0][1]*(R[1][0]*R[2][2] - R[1][2]*R[2][0])
      + R[0][2]*(R[1][0]*R[2][1] - R[1][1]*R[2][0]);
    if (det < 0.0) {
#pragma unroll
      for (int i = 0; i < 3; ++i)
#pragma unroll
        for (int j = 0; j < 3; ++j)
          R[i][j] -= 2.0 * V[i][2] * U[j][2];
    }
  }
#pragma unroll
  for (int i = 0; i < 3; ++i)
    t[i] = cb[i] - (R[i][0]*sb[0] + R[i][1]*sb[1] + R[i][2]*sb[2]);
}

// Block-redundant solve helper: reduce partials (512 rows x 16) for all 8
// batches, run Kabsch on lane j==0 of each 32-thread group, publish R,t to
// s_RT and the scalar err sum to s_val. Requires blockDim >= 256.
// Caller must __syncthreads() after.
__device__ __forceinline__ void solve_head(const float* __restrict__ PT,
                                           float s_RT[8][12], float s_val[8],
                                           int tid) {
  if (tid < 256) {
    const int sb2 = tid >> 5;
    const int j = tid & 31;
    float acc[16];
    const float* P0 = PT + ((sb2 << 6) + j) * 16;
    const float* P1 = P0 + 32 * 16;
#pragma unroll
    for (int k = 0; k < 16; ++k) acc[k] = P0[k] + P1[k];
#pragma unroll
    for (int k = 0; k < 16; ++k) {
      float v = acc[k];
      v += __shfl_xor(v, 16, 64);
      v += __shfl_xor(v, 8, 64);
      v += __shfl_xor(v, 4, 64);
      v += __shfl_xor(v, 2, 64);
      v += __shfl_xor(v, 1, 64);
      acc[k] = v;
    }
    if (j == 0) {
      s_val[sb2] = acc[0];
      double Ss[3] = {acc[1], acc[2], acc[3]};
      double Sc[3] = {acc[4], acc[5], acc[6]};
      double Pm[9];
#pragma unroll
      for (int k = 0; k < 9; ++k) Pm[k] = acc[7 + k];
      double R[3][3], tr[3];
      kabsch3(Pm, Ss, Sc, R, tr);
#pragma unroll
      for (int i = 0; i < 3; ++i)
#pragma unroll
        for (int jj = 0; jj < 3; ++jj) s_RT[sb2][i * 3 + jj] = (float)R[i][jj];
#pragma unroll
      for (int i = 0; i < 3; ++i) s_RT[sb2][9 + i] = (float)tr[i];
    }
  }
}

__global__ void k_prep(const float* __restrict__ srcInit, const float* __restrict__ dst,
                       float* __restrict__ ws, float* __restrict__ out) {
  const int gid = blockIdx.x * blockDim.x + threadIdx.x;
  const int stride = gridDim.x * blockDim.x;
  float4* packed = (float4*)(ws + WS_PACKED);
  for (int i = gid; i < NBATCH * NPTS; i += stride) {
    const int b = i >> 12, m = i & (NPTS - 1);
    const float dx = dst[b * 3 * NPTS + m];
    const float dy = dst[b * 3 * NPTS + NPTS + m];
    const float dz = dst[b * 3 * NPTS + 2 * NPTS + m];
    const float nyy = -fmaf(dx, dx, fmaf(dy, dy, dz * dz));
    packed[i] = make_float4(dx, dy, dz, nyy);
  }
  const float4* s4 = (const float4*)srcInit;
  float4* w4 = (float4*)(ws + WS_SRC);
  float4* o4 = (float4*)out;
  for (int i = gid; i < (NBATCH * 3 * NPTS) / 4; i += stride) {
    float4 v = s4[i];
    w4[i] = v;
    o4[i] = v;  // output 0: srcInit pass-through
  }
  if (gid == 0) {
    ws[WS_STATE + 0] = 0.0f;  // slot0 prev_err (= err_{-1})
    ws[WS_STATE + 1] = 0.0f;  // slot0 done_{-1}
  }
}

// grid (64,8) x 1024 thr, launched 10x with it=0..9.
// 16 waves/block: 64 src points x 16 m-slices of 256 dst points each.
// 512 blocks = 2 blocks/CU x 16 waves = 32 waves/CU (full occupancy) --
// latency hiding via TLP (round-7 lesson: ILP pipelining cost occupancy).
// Dispatch it: [it>0] block-redundant solve of fit_{it-1} from partials
// slot (it-1)&1, apply R,t, then NN scan writing partials slot it&1.
__global__ void __launch_bounds__(1024, 8) k_nn(float* __restrict__ ws, int it) {
  const int b = blockIdx.y;
  const int chunk = blockIdx.x;
  const int tid = threadIdx.x;
  const int slice = tid >> 6;    // 0..15
  const int pidx = tid & 63;
  const int n = (chunk << 6) + pidx;

  __shared__ float rv[16][64];
  __shared__ int ri[16][64];
  __shared__ float s_RT[8][12];
  __shared__ float s_val[8];
  __shared__ float s_done_new;

  float* state = ws + WS_STATE;
  float* src = ws + WS_SRC;
  const int sbase = b * 3 * NPTS + n;
  float sx = src[sbase];
  float sy = src[sbase + NPTS];
  float sz = src[sbase + 2 * NPTS];

  bool skip_scan = false;
  if (it > 0) {
    const int ps = (it - 1) & 1;
    const float prev_err = state[ps * 2 + 0];   // err_{it-2}
    const float done_prev = state[ps * 2 + 1];  // done_{it-2}
    if (done_prev != 0.0f) {
      // fully frozen: copy state forward, touch nothing else
      if (blockIdx.x == 0 && blockIdx.y == 0 && tid == 0) {
        state[(it & 1) * 2 + 0] = prev_err;
        state[(it & 1) * 2 + 1] = 1.0f;
      }
      return;
    }
    // block-redundant solve of fit_{it-1}
    solve_head(ws + WS_PART + ps * 8192, s_RT, s_val, tid);
    __syncthreads();  // publish s_RT/s_val; also: all src reads above done
    if (tid == 0) {
      float total = 0.0f;
#pragma unroll
      for (int bb = 0; bb < 8; ++bb) total += s_val[bb];
      const float err = total * (1.0f / 32768.0f);  // err_{it-1}
      const float dn = (fabsf(prev_err - err) < 0.001f) ? 1.0f : 0.0f;
      s_done_new = dn;
      if (blockIdx.x == 0 && blockIdx.y == 0) {
        state[(it & 1) * 2 + 0] = err;
        state[(it & 1) * 2 + 1] = dn;
      }
    }
    __syncthreads();  // publish s_done_new
    // apply R_{it-1},t (done_{it-2}==0 here)
    const float* RT = s_RT[b];
    const float nx = fmaf(RT[0], sx, fmaf(RT[1], sy, fmaf(RT[2], sz, RT[9])));
    const float ny = fmaf(RT[3], sx, fmaf(RT[4], sy, fmaf(RT[5], sz, RT[10])));
    const float nz = fmaf(RT[6], sx, fmaf(RT[7], sy, fmaf(RT[8], sz, RT[11])));
    sx = nx; sy = ny; sz = nz;
    if (slice == 0) {  // safe: all reads completed before first barrier
      src[sbase] = sx;
      src[sbase + NPTS] = sy;
      src[sbase + 2 * NPTS] = sz;
    }
    skip_scan = (s_done_new != 0.0f);
  }

  if (skip_scan) return;  // uniform across grid

  const float4* __restrict__ packed = ((const float4*)(ws + WS_PACKED)) + b * NPTS;
  const float s2x = 2.0f * sx, s2y = 2.0f * sy, s2z = 2.0f * sz;
  const int m0 = slice << 8;   // 256 dst points per slice
  const float4* __restrict__ bp = packed + m0;

  float best = -3.0e38f;
  int gwin = 0;
#pragma unroll 2
  for (int g = 0; g < 32; ++g) {
    const float4 d0 = bp[(g << 3) + 0];
    const float4 d1 = bp[(g << 3) + 1];
    const float4 d2 = bp[(g << 3) + 2];
    const float4 d3 = bp[(g << 3) + 3];
    const float4 d4 = bp[(g << 3) + 4];
    const float4 d5 = bp[(g << 3) + 5];
    const float4 d6 = bp[(g << 3) + 6];
    const float4 d7 = bp[(g << 3) + 7];
    const float p0 = fmaf(s2x, d0.x, fmaf(s2y, d0.y, fmaf(s2z, d0.z, d0.w)));
    const float p1 = fmaf(s2x, d1.x, fmaf(s2y, d1.y, fmaf(s2z, d1.z, d1.w)));
    const float p2 = fmaf(s2x, d2.x, fmaf(s2y, d2.y, fmaf(s2z, d2.z, d2.w)));
    const float p3 = fmaf(s2x, d3.x, fmaf(s2y, d3.y, fmaf(s2z, d3.z, d3.w)));
    const float p4 = fmaf(s2x, d4.x, fmaf(s2y, d4.y, fmaf(s2z, d4.z, d4.w)));
    const float p5 = fmaf(s2x, d5.x, fmaf(s2y, d5.y, fmaf(s2z, d5.z, d5.w)));
    const float p6 = fmaf(s2x, d6.x, fmaf(s2y, d6.y, fmaf(s2z, d6.z, d6.w)));
    const float p7 = fmaf(s2x, d7.x, fmaf(s2y, d7.y, fmaf(s2z, d7.z, d7.w)));
    // max3-friendly tree (v_max3_f32 fusion)
    const float t0 = fmaxf(fmaxf(p0, p1), p2);
    const float t1 = fmaxf(fmaxf(p3, p4), p5);
    const float t2 = fmaxf(p6, p7);
    const float gm = fmaxf(fmaxf(t0, t1), t2);
    // strict > with ascending g: first group attaining the max wins.
    if (gm > best) { best = gm; gwin = g; }
  }
  // Exact first-max index within winning group (bit-identical recompute,
  // descending j so smallest index wins).
  const int gbase = m0 + (gwin << 3);
  const float4* __restrict__ gp = packed + gbase;
  int bi = gbase;
#pragma unroll
  for (int j = 7; j >= 0; --j) {
    const float4 d = gp[j];
    const float p = fmaf(s2x, d.x, fmaf(s2y, d.y, fmaf(s2z, d.z, d.w)));
    if (p == best) bi = gbase + j;
  }

  rv[slice][pidx] = best;
  ri[slice][pidx] = bi;
  __syncthreads();

  if (slice == 0) {
    float bv = rv[0][pidx];
    int bidx = ri[0][pidx];
#pragma unroll
    for (int s = 1; s < 16; ++s) {
      const float v = rv[s][pidx];
      if (v > bv) { bv = v; bidx = ri[s][pidx]; }  // ascending slice: first max
    }
    const float4 c = packed[bidx];
    const float xx = fmaf(sx, sx, fmaf(sy, sy, sz * sz));
    float vals[16];
    vals[0] = bv - xx;          // val = max(2 s.d - yy) - xx
    vals[1] = sx;  vals[2] = sy;  vals[3] = sz;
    vals[4] = c.x; vals[5] = c.y; vals[6] = c.z;
    vals[7]  = sx * c.x; vals[8]  = sx * c.y; vals[9]  = sx * c.z;
    vals[10] = sy * c.x; vals[11] = sy * c.y; vals[12] = sy * c.z;
    vals[13] = sz * c.x; vals[14] = sz * c.y; vals[15] = sz * c.z;
#pragma unroll
    for (int k = 0; k < 16; ++k) {
      float v = vals[k];
#pragma unroll
      for (int off = 32; off >= 1; off >>= 1) v += __shfl_xor(v, off, 64);
      vals[k] = v;
    }
    if (pidx == 0) {
      float* Pp = ws + WS_PART + (it & 1) * 8192 + ((b << 6) + chunk) * 16;
#pragma unroll
      for (int k = 0; k < 16; ++k) Pp[k] = vals[k];
    }
  }
}

// grid (16,8) x 256 thr (= dispatch 10): block-redundant solve of fit_9 from
// partials slot 1 (gated on done_8 in state slot 1), apply, write final src,
// emit partials for the final Kabsch.
__global__ void __launch_bounds__(256, 4) k_final(const float* __restrict__ srcInit,
                                                  float* __restrict__ ws,
                                                  float* __restrict__ out) {
  const int b = blockIdx.y;
  const int chunk = blockIdx.x;
  const int tid = threadIdx.x;
  const int n = (chunk << 8) + tid;
  __shared__ float red[4][15];
  __shared__ float s_RT[8][12];
  __shared__ float s_val[8];
  float* state = ws + WS_STATE;
  const float done8 = state[2 + 1];  // slot1.done (written by dispatch it=9)
  const int sbase = b * 3 * NPTS + n;
  float sx = ws[WS_SRC + sbase];
  float sy = ws[WS_SRC + sbase + NPTS];
  float sz = ws[WS_SRC + sbase + 2 * NPTS];
  if (done8 == 0.0f) {
    solve_head(ws + WS_PART + 8192, s_RT, s_val, tid);  // fit_9 from slot1
    __syncthreads();
    const float* RT = s_RT[b];
    const float nx = fmaf(RT[0], sx, fmaf(RT[1], sy, fmaf(RT[2], sz, RT[9])));
    const float ny = fmaf(RT[3], sx, fmaf(RT[4], sy, fmaf(RT[5], sz, RT[10])));
    const float nz = fmaf(RT[6], sx, fmaf(RT[7], sy, fmaf(RT[8], sz, RT[11])));
    sx = nx; sy = ny; sz = nz;
  }
  out[98304 + sbase] = sx;
  out[98304 + sbase + NPTS] = sy;
  out[98304 + sbase + 2 * NPTS] = sz;

  const float ax = srcInit[sbase];
  const float ay = srcInit[sbase + NPTS];
  const float az = srcInit[sbase + 2 * NPTS];
  float vals[15];
  vals[0] = ax; vals[1] = ay; vals[2] = az;
  vals[3] = sx; vals[4] = sy; vals[5] = sz;
  vals[6]  = ax * sx; vals[7]  = ax * sy; vals[8]  = ax * sz;
  vals[9]  = ay * sx; vals[10] = ay * sy; vals[11] = ay * sz;
  vals[12] = az * sx; vals[13] = az * sy; vals[14] = az * sz;
  const int w = tid >> 6, lane = tid & 63;
#pragma unroll
  for (int k = 0; k < 15; ++k) {
    float v = vals[k];
#pragma unroll
    for (int off = 32; off >= 1; off >>= 1) v += __shfl_xor(v, off, 64);
    vals[k] = v;
  }
  if (lane == 0) {
#pragma unroll
    for (int k = 0; k < 15; ++k) red[w][k] = vals[k];
  }
  __syncthreads();
  if (tid == 0) {
    float* FP = ws + WS_FPART + ((b << 4) + chunk) * 15;
#pragma unroll
    for (int k = 0; k < 15; ++k) FP[k] = red[0][k] + red[1][k] + red[2][k] + red[3][k];
  }
}

__global__ void __launch_bounds__(256) k_fsolve(float* __restrict__ ws, float* __restrict__ out) {
  const int t = threadIdx.x;
  const int b = t >> 5;
  const int j = t & 31;
  float acc[15];
  if (j < 16) {
    const float* F = ws + WS_FPART + ((b << 4) + j) * 15;
#pragma unroll
    for (int k = 0; k < 15; ++k) acc[k] = F[k];
  } else {
#pragma unroll
    for (int k = 0; k < 15; ++k) acc[k] = 0.0f;
  }
#pragma unroll
  for (int k = 0; k < 15; ++k) {
    float v = acc[k];
    v += __shfl_xor(v, 16, 64);
    v += __shfl_xor(v, 8, 64);
    v += __shfl_xor(v, 4, 64);
    v += __shfl_xor(v, 2, 64);
    v += __shfl_xor(v, 1, 64);
    acc[k] = v;
  }
  if (j == 0) {
    double Ss[3] = {acc[0], acc[1], acc[2]};
    double Sc[3] = {acc[3], acc[4], acc[5]};
    double Pm[9];
#pragma unroll
    for (int k = 0; k < 9; ++k) Pm[k] = acc[6 + k];
    double R[3][3], tr[3];
    kabsch3(Pm, Ss, Sc, R, tr);
#pragma unroll
    for (int i = 0; i < 3; ++i) {
#pragma unroll
      for (int jj = 0; jj < 3; ++jj) {
        out[196608 + b * 9 + i * 3 + jj] = (float)R[i][jj];       // rotation_ab
        out[196704 + b * 9 + i * 3 + jj] = (float)R[jj][i];       // rotation_ba = R^T
      }
      out[196680 + b * 3 + i] = (float)tr[i];                     // translation_ab
      out[196776 + b * 3 + i] =
          (float)(-(R[0][i] * tr[0] + R[1][i] * tr[1] + R[2][i] * tr[2]));  // -R^T t
    }
  }
}

extern "C" void kernel_launch(void* const* d_in, const int* in_sizes, int n_in,
                              void* d_out, int out_size, void* d_ws, size_t ws_size,
                              hipStream_t stream) {
  (void)in_sizes; (void)n_in; (void)out_size; (void)ws_size;
  const float* srcInit = (const float*)d_in[0];
  const float* dst = (const float*)d_in[1];
  float* out = (float*)d_out;
  float* ws = (float*)d_ws;

  k_prep<<<256, 256, 0, stream>>>(srcInit, dst, ws, out);
  for (int it = 0; it < 10; ++it)
    k_nn<<<dim3(64, 8), 1024, 0, stream>>>(ws, it);
  k_final<<<dim3(16, 8), 256, 0, stream>>>(srcInit, ws, out);
  k_fsolve<<<1, 256, 0, stream>>>(ws, out);
}

// Round 9
// 189.694 us; speedup vs baseline: 1.2297x; 1.1655x over previous
//
#include <hip/hip_runtime.h>
#include <math.h>

#define NPTS 4096
#define NBATCH 8

// ws layout (float offsets)
#define WS_SRC    0          // [8][3][4096]                 = 98304
#define WS_PACKED 98304      // [8][4096] float4             = 131072 floats
#define WS_PART   229376     // 2 x [512][16] ping-pong      = 16384 floats
#define WS_FPART  229376     // overlaps PART slot0 (dead by k_final)
#define WS_STATE  245760     // slot0 {prev_err,done} slot1 {prev_err,done}
#define WS_PVAL   245764     // 2 x [512] ping-pong val partials (contiguous)

__device__ __forceinline__ void jrot(double A[3][3], double V[3][3], int p, int q) {
  double apq = A[p][q];
  if (fabs(apq) > 0.0) {
    double tau = (A[q][q] - A[p][p]) / (2.0 * apq);
    double tt = (tau >= 0.0 ? 1.0 : -1.0) / (fabs(tau) + sqrt(1.0 + tau * tau));
    double c = 1.0 / sqrt(1.0 + tt * tt);
    double s = tt * c;
#pragma unroll
    for (int k = 0; k < 3; ++k) { double akp = A[k][p], akq = A[k][q]; A[k][p] = c*akp - s*akq; A[k][q] = s*akp + c*akq; }
#pragma unroll
    for (int k = 0; k < 3; ++k) { double apk = A[p][k], aqk = A[q][k]; A[p][k] = c*apk - s*aqk; A[q][k] = s*apk + c*aqk; }
#pragma unroll
    for (int k = 0; k < 3; ++k) { double vkp = V[k][p], vkq = V[k][q]; V[k][p] = c*vkp - s*vkq; V[k][q] = s*vkp + c*vkq; }
  }
}

// P = sum s_i c_j (row-major 9), Ss = sum s, Sc = sum c, n = 4096.
// Kabsch R (src->corr), t = cbar - R sbar; matches svd+reflection-fix reference.
__device__ void kabsch3(const double P[9], const double Ss[3], const double Sc[3],
                        double R[3][3], double t[3]) {
  const double invn = 1.0 / 4096.0;
  double sb[3], cb[3];
#pragma unroll
  for (int i = 0; i < 3; ++i) { sb[i] = Ss[i] * invn; cb[i] = Sc[i] * invn; }
  double H[3][3];
#pragma unroll
  for (int i = 0; i < 3; ++i)
#pragma unroll
    for (int j = 0; j < 3; ++j)
      H[i][j] = P[i * 3 + j] - Ss[i] * cb[j];

  double A[3][3];
  double V[3][3] = {{1,0,0},{0,1,0},{0,0,1}};
#pragma unroll
  for (int i = 0; i < 3; ++i)
#pragma unroll
    for (int j = 0; j < 3; ++j)
      A[i][j] = H[0][i]*H[0][j] + H[1][i]*H[1][j] + H[2][i]*H[2][j];

  for (int sw = 0; sw < 6; ++sw) {
    jrot(A, V, 0, 1);
    jrot(A, V, 0, 2);
    jrot(A, V, 1, 2);
  }
  double l0 = A[0][0], l1 = A[1][1], l2 = A[2][2];
  if (l0 < l1) {
    double tm = l0; l0 = l1; l1 = tm;
#pragma unroll
    for (int k = 0; k < 3; ++k) { double tv = V[k][0]; V[k][0] = V[k][1]; V[k][1] = tv; }
  }
  if (l0 < l2) {
    double tm = l0; l0 = l2; l2 = tm;
#pragma unroll
    for (int k = 0; k < 3; ++k) { double tv = V[k][0]; V[k][0] = V[k][2]; V[k][2] = tv; }
  }
  if (l1 < l2) {
    double tm = l1; l1 = l2; l2 = tm;
#pragma unroll
    for (int k = 0; k < 3; ++k) { double tv = V[k][1]; V[k][1] = V[k][2]; V[k][2] = tv; }
  }
  double U[3][3];
  double nrm0 = 0.0, nrm2 = 0.0;
#pragma unroll
  for (int k = 0; k < 3; ++k) {
    double ux = H[0][0]*V[0][k] + H[0][1]*V[1][k] + H[0][2]*V[2][k];
    double uy = H[1][0]*V[0][k] + H[1][1]*V[1][k] + H[1][2]*V[2][k];
    double uz = H[2][0]*V[0][k] + H[2][1]*V[1][k] + H[2][2]*V[2][k];
    double nn2 = sqrt(ux*ux + uy*uy + uz*uz);
    if (k == 0) nrm0 = nn2;
    if (k == 2) nrm2 = nn2;
    double inv = (nn2 > 0.0) ? 1.0 / nn2 : 0.0;
    U[0][k] = ux * inv; U[1][k] = uy * inv; U[2][k] = uz * inv;
  }
  if (nrm0 <= 1e-30) {
#pragma unroll
    for (int i = 0; i < 3; ++i)
#pragma unroll
      for (int j = 0; j < 3; ++j)
        R[i][j] = (i == j) ? 1.0 : 0.0;
  } else {
    if (nrm2 <= nrm0 * 1e-12) {
      double cx = U[1][0]*U[2][1] - U[2][0]*U[1][1];
      double cy = U[2][0]*U[0][1] - U[0][0]*U[2][1];
      double cz = U[0][0]*U[1][1] - U[1][0]*U[0][1];
      double cn = sqrt(cx*cx + cy*cy + cz*cz);
      double inv = (cn > 0.0) ? 1.0 / cn : 0.0;
      U[0][2] = cx * inv; U[1][2] = cy * inv; U[2][2] = cz * inv;
    }
#pragma unroll
    for (int i = 0; i < 3; ++i)
#pragma unroll
      for (int j = 0; j < 3; ++j)
        R[i][j] = V[i][0]*U[j][0] + V[i][1]*U[j][1] + V[i][2]*U[j][2];
    double det =
        R[0][0]*(R[1][1]*R[2][2] - R[1][2]*R[2][1])
      - R[0][1]*(R[1][0]*R[2][2] - R[1][2]*R[2][0])
      + R[0][2]*(R[1][0]*R[2][1] - R[1][1]*R[2][0]);
    if (det < 0.0) {
#pragma unroll
      for (int i = 0; i < 3; ++i)
#pragma unroll
        for (int j = 0; j < 3; ++j)
          R[i][j] -= 2.0 * V[i][2] * U[j][2];
    }
  }
#pragma unroll
  for (int i = 0; i < 3; ++i)
    t[i] = cb[i] - (R[i][0]*sb[0] + R[i][1]*sb[1] + R[i][2]*sb[2]);
}

// Old-style block-redundant solve over all 8 batches (used only by k_final,
// blockDim >= 256). Caller must __syncthreads() after.
__device__ __forceinline__ void solve_head(const float* __restrict__ PT,
                                           float s_RT[8][12], float s_val[8],
                                           int tid) {
  if (tid < 256) {
    const int sb2 = tid >> 5;
    const int j = tid & 31;
    float acc[16];
    const float* P0 = PT + ((sb2 << 6) + j) * 16;
    const float* P1 = P0 + 32 * 16;
#pragma unroll
    for (int k = 0; k < 16; ++k) acc[k] = P0[k] + P1[k];
#pragma unroll
    for (int k = 0; k < 16; ++k) {
      float v = acc[k];
      v += __shfl_xor(v, 16, 64);
      v += __shfl_xor(v, 8, 64);
      v += __shfl_xor(v, 4, 64);
      v += __shfl_xor(v, 2, 64);
      v += __shfl_xor(v, 1, 64);
      acc[k] = v;
    }
    if (j == 0) {
      s_val[sb2] = acc[0];
      double Ss[3] = {acc[1], acc[2], acc[3]};
      double Sc[3] = {acc[4], acc[5], acc[6]};
      double Pm[9];
#pragma unroll
      for (int k = 0; k < 9; ++k) Pm[k] = acc[7 + k];
      double R[3][3], tr[3];
      kabsch3(Pm, Ss, Sc, R, tr);
#pragma unroll
      for (int i = 0; i < 3; ++i)
#pragma unroll
        for (int jj = 0; jj < 3; ++jj) s_RT[sb2][i * 3 + jj] = (float)R[i][jj];
#pragma unroll
      for (int i = 0; i < 3; ++i) s_RT[sb2][9 + i] = (float)tr[i];
    }
  }
}

__global__ void k_prep(const float* __restrict__ srcInit, const float* __restrict__ dst,
                       float* __restrict__ ws, float* __restrict__ out) {
  const int gid = blockIdx.x * blockDim.x + threadIdx.x;
  const int stride = gridDim.x * blockDim.x;
  float4* packed = (float4*)(ws + WS_PACKED);
  for (int i = gid; i < NBATCH * NPTS; i += stride) {
    const int b = i >> 12, m = i & (NPTS - 1);
    const float dx = dst[b * 3 * NPTS + m];
    const float dy = dst[b * 3 * NPTS + NPTS + m];
    const float dz = dst[b * 3 * NPTS + 2 * NPTS + m];
    const float nyy = -fmaf(dx, dx, fmaf(dy, dy, dz * dz));
    packed[i] = make_float4(dx, dy, dz, nyy);
  }
  const float4* s4 = (const float4*)srcInit;
  float4* w4 = (float4*)(ws + WS_SRC);
  float4* o4 = (float4*)out;
  for (int i = gid; i < (NBATCH * 3 * NPTS) / 4; i += stride) {
    float4 v = s4[i];
    w4[i] = v;
    o4[i] = v;  // output 0: srcInit pass-through
  }
  if (gid == 0) {
    ws[WS_STATE + 0] = 0.0f;  // slot0 prev_err (= err_{-1})
    ws[WS_STATE + 1] = 0.0f;  // slot0 done_{-1}
  }
}

// grid (64,8) x 512 thr, launched 10x with it=0..9. R4 scan structure.
// Lean solve head: wave 0 reduces ONLY batch b's 64 partial rows (4 KB) and
// runs one Kabsch; wave 1 reduces the contiguous PVAL[512] (2 KB) for
// err/done. 6 KB/block instead of 32 KB, one barrier instead of two.
__global__ void __launch_bounds__(512, 4) k_nn(float* __restrict__ ws, int it) {
  const int b = blockIdx.y;
  const int chunk = blockIdx.x;
  const int tid = threadIdx.x;
  const int slice = tid >> 6;
  const int pidx = tid & 63;
  const int n = (chunk << 6) + pidx;

  __shared__ float rv[8][64];
  __shared__ int ri[8][64];
  __shared__ float s_RT[12];
  __shared__ float s_done_new;

  float* state = ws + WS_STATE;
  float* src = ws + WS_SRC;
  const int sbase = b * 3 * NPTS + n;
  float sx = src[sbase];
  float sy = src[sbase + NPTS];
  float sz = src[sbase + 2 * NPTS];

  bool skip_scan = false;
  if (it > 0) {
    const int ps = (it - 1) & 1;
    const float prev_err = state[ps * 2 + 0];   // err_{it-2}
    const float done_prev = state[ps * 2 + 1];  // done_{it-2}
    if (done_prev != 0.0f) {
      // fully frozen: copy state forward, touch nothing else
      if (blockIdx.x == 0 && blockIdx.y == 0 && tid == 0) {
        state[(it & 1) * 2 + 0] = prev_err;
        state[(it & 1) * 2 + 1] = 1.0f;
      }
      return;
    }
    // --- lean per-batch solve of fit_{it-1} ---
    if (tid < 64) {
      // batch b's 64 partial rows: lane tid reads row (b<<6)+tid (64 B)
      const float* row = ws + WS_PART + ps * 8192 + ((b << 6) + tid) * 16;
      const float4 r0 = *(const float4*)(row + 0);
      const float4 r1 = *(const float4*)(row + 4);
      const float4 r2 = *(const float4*)(row + 8);
      const float4 r3 = *(const float4*)(row + 12);
      float a[16] = {r0.x, r0.y, r0.z, r0.w, r1.x, r1.y, r1.z, r1.w,
                     r2.x, r2.y, r2.z, r2.w, r3.x, r3.y, r3.z, r3.w};
#pragma unroll
      for (int k = 1; k < 16; ++k) {  // a[0]=val unused here
        float v = a[k];
        v += __shfl_xor(v, 32, 64);
        v += __shfl_xor(v, 16, 64);
        v += __shfl_xor(v, 8, 64);
        v += __shfl_xor(v, 4, 64);
        v += __shfl_xor(v, 2, 64);
        v += __shfl_xor(v, 1, 64);
        a[k] = v;
      }
      if (tid == 0) {
        double Ss[3] = {a[1], a[2], a[3]};
        double Sc[3] = {a[4], a[5], a[6]};
        double Pm[9];
#pragma unroll
        for (int k = 0; k < 9; ++k) Pm[k] = a[7 + k];
        double R[3][3], tr[3];
        kabsch3(Pm, Ss, Sc, R, tr);
#pragma unroll
        for (int i = 0; i < 3; ++i)
#pragma unroll
          for (int jj = 0; jj < 3; ++jj) s_RT[i * 3 + jj] = (float)R[i][jj];
#pragma unroll
        for (int i = 0; i < 3; ++i) s_RT[9 + i] = (float)tr[i];
      }
    } else if (tid < 128) {
      // err: contiguous 512-float PVAL, lane l reads l + 64*j (coalesced)
      const int l = tid - 64;
      const float* PV = ws + WS_PVAL + ps * 512;
      float s = 0.0f;
#pragma unroll
      for (int j = 0; j < 8; ++j) s += PV[l + (j << 6)];
      s += __shfl_xor(s, 32, 64);
      s += __shfl_xor(s, 16, 64);
      s += __shfl_xor(s, 8, 64);
      s += __shfl_xor(s, 4, 64);
      s += __shfl_xor(s, 2, 64);
      s += __shfl_xor(s, 1, 64);
      if (tid == 64) {
        const float err = s * (1.0f / 32768.0f);  // err_{it-1}
        const float dn = (fabsf(prev_err - err) < 0.001f) ? 1.0f : 0.0f;
        s_done_new = dn;
        if (blockIdx.x == 0 && blockIdx.y == 0) {
          state[(it & 1) * 2 + 0] = err;
          state[(it & 1) * 2 + 1] = dn;
        }
      }
    }
    __syncthreads();  // publish s_RT / s_done_new; all src reads above done
    // apply R_{it-1},t (done_{it-2}==0 here)
    const float* RT = s_RT;
    const float nx = fmaf(RT[0], sx, fmaf(RT[1], sy, fmaf(RT[2], sz, RT[9])));
    const float ny = fmaf(RT[3], sx, fmaf(RT[4], sy, fmaf(RT[5], sz, RT[10])));
    const float nz = fmaf(RT[6], sx, fmaf(RT[7], sy, fmaf(RT[8], sz, RT[11])));
    sx = nx; sy = ny; sz = nz;
    if (slice == 0) {  // safe: all reads completed before the barrier
      src[sbase] = sx;
      src[sbase + NPTS] = sy;
      src[sbase + 2 * NPTS] = sz;
    }
    skip_scan = (s_done_new != 0.0f);
  }

  if (skip_scan) return;  // uniform across grid

  const float4* __restrict__ packed = ((const float4*)(ws + WS_PACKED)) + b * NPTS;
  const float s2x = 2.0f * sx, s2y = 2.0f * sy, s2z = 2.0f * sz;
  const int m0 = slice << 9;
  const float4* __restrict__ bp = packed + m0;

  float best = -3.0e38f;
  int gwin = 0;
#pragma unroll 2
  for (int g = 0; g < 64; ++g) {
    const float4 d0 = bp[(g << 3) + 0];
    const float4 d1 = bp[(g << 3) + 1];
    const float4 d2 = bp[(g << 3) + 2];
    const float4 d3 = bp[(g << 3) + 3];
    const float4 d4 = bp[(g << 3) + 4];
    const float4 d5 = bp[(g << 3) + 5];
    const float4 d6 = bp[(g << 3) + 6];
    const float4 d7 = bp[(g << 3) + 7];
    const float p0 = fmaf(s2x, d0.x, fmaf(s2y, d0.y, fmaf(s2z, d0.z, d0.w)));
    const float p1 = fmaf(s2x, d1.x, fmaf(s2y, d1.y, fmaf(s2z, d1.z, d1.w)));
    const float p2 = fmaf(s2x, d2.x, fmaf(s2y, d2.y, fmaf(s2z, d2.z, d2.w)));
    const float p3 = fmaf(s2x, d3.x, fmaf(s2y, d3.y, fmaf(s2z, d3.z, d3.w)));
    const float p4 = fmaf(s2x, d4.x, fmaf(s2y, d4.y, fmaf(s2z, d4.z, d4.w)));
    const float p5 = fmaf(s2x, d5.x, fmaf(s2y, d5.y, fmaf(s2z, d5.z, d5.w)));
    const float p6 = fmaf(s2x, d6.x, fmaf(s2y, d6.y, fmaf(s2z, d6.z, d6.w)));
    const float p7 = fmaf(s2x, d7.x, fmaf(s2y, d7.y, fmaf(s2z, d7.z, d7.w)));
    const float gm = fmaxf(fmaxf(fmaxf(p0, p1), fmaxf(p2, p3)),
                           fmaxf(fmaxf(p4, p5), fmaxf(p6, p7)));
    // strict > with ascending g: first group attaining the max wins.
    if (gm > best) { best = gm; gwin = g; }
  }
  // Exact first-max index within winning group (bit-identical recompute,
  // descending j so smallest index wins).
  const int gb = m0 + (gwin << 3);
  const float4* __restrict__ gp = packed + gb;
  int bi = gb;
#pragma unroll
  for (int j = 7; j >= 0; --j) {
    const float4 d = gp[j];
    const float p = fmaf(s2x, d.x, fmaf(s2y, d.y, fmaf(s2z, d.z, d.w)));
    if (p == best) bi = gb + j;
  }

  rv[slice][pidx] = best;
  ri[slice][pidx] = bi;
  __syncthreads();

  if (slice == 0) {
    float bv = rv[0][pidx];
    int bidx = ri[0][pidx];
#pragma unroll
    for (int s = 1; s < 8; ++s) {
      const float v = rv[s][pidx];
      if (v > bv) { bv = v; bidx = ri[s][pidx]; }  // ascending slice: first max
    }
    const float4 c = packed[bidx];
    const float xx = fmaf(sx, sx, fmaf(sy, sy, sz * sz));
    float vals[16];
    vals[0] = bv - xx;          // val = max(2 s.d - yy) - xx
    vals[1] = sx;  vals[2] = sy;  vals[3] = sz;
    vals[4] = c.x; vals[5] = c.y; vals[6] = c.z;
    vals[7]  = sx * c.x; vals[8]  = sx * c.y; vals[9]  = sx * c.z;
    vals[10] = sy * c.x; vals[11] = sy * c.y; vals[12] = sy * c.z;
    vals[13] = sz * c.x; vals[14] = sz * c.y; vals[15] = sz * c.z;
#pragma unroll
    for (int k = 0; k < 16; ++k) {
      float v = vals[k];
#pragma unroll
      for (int off = 32; off >= 1; off >>= 1) v += __shfl_xor(v, off, 64);
      vals[k] = v;
    }
    if (pidx == 0) {
      float* Pp = ws + WS_PART + (it & 1) * 8192 + ((b << 6) + chunk) * 16;
#pragma unroll
      for (int k = 0; k < 16; ++k) Pp[k] = vals[k];
      ws[WS_PVAL + (it & 1) * 512 + (b << 6) + chunk] = vals[0];
    }
  }
}

// grid (16,8) x 256 thr (= dispatch 10): block-redundant solve of fit_9 from
// partials slot 1 (gated on done_8 in state slot 1), apply, write final src,
// emit partials for the final Kabsch.
__global__ void __launch_bounds__(256, 4) k_final(const float* __restrict__ srcInit,
                                                  float* __restrict__ ws,
                                                  float* __restrict__ out) {
  const int b = blockIdx.y;
  const int chunk = blockIdx.x;
  const int tid = threadIdx.x;
  const int n = (chunk << 8) + tid;
  __shared__ float red[4][15];
  __shared__ float s_RT[8][12];
  __shared__ float s_val[8];
  float* state = ws + WS_STATE;
  const float done8 = state[2 + 1];  // slot1.done (written by dispatch it=9)
  const int sbase = b * 3 * NPTS + n;
  float sx = ws[WS_SRC + sbase];
  float sy = ws[WS_SRC + sbase + NPTS];
  float sz = ws[WS_SRC + sbase + 2 * NPTS];
  if (done8 == 0.0f) {
    solve_head(ws + WS_PART + 8192, s_RT, s_val, tid);  // fit_9 from slot1
    __syncthreads();
    const float* RT = s_RT[b];
    const float nx = fmaf(RT[0], sx, fmaf(RT[1], sy, fmaf(RT[2], sz, RT[9])));
    const float ny = fmaf(RT[3], sx, fmaf(RT[4], sy, fmaf(RT[5], sz, RT[10])));
    const float nz = fmaf(RT[6], sx, fmaf(RT[7], sy, fmaf(RT[8], sz, RT[11])));
    sx = nx; sy = ny; sz = nz;
  }
  out[98304 + sbase] = sx;
  out[98304 + sbase + NPTS] = sy;
  out[98304 + sbase + 2 * NPTS] = sz;

  const float ax = srcInit[sbase];
  const float ay = srcInit[sbase + NPTS];
  const float az = srcInit[sbase + 2 * NPTS];
  float vals[15];
  vals[0] = ax; vals[1] = ay; vals[2] = az;
  vals[3] = sx; vals[4] = sy; vals[5] = sz;
  vals[6]  = ax * sx; vals[7]  = ax * sy; vals[8]  = ax * sz;
  vals[9]  = ay * sx; vals[10] = ay * sy; vals[11] = ay * sz;
  vals[12] = az * sx; vals[13] = az * sy; vals[14] = az * sz;
  const int w = tid >> 6, lane = tid & 63;
#pragma unroll
  for (int k = 0; k < 15; ++k) {
    float v = vals[k];
#pragma unroll
    for (int off = 32; off >= 1; off >>= 1) v += __shfl_xor(v, off, 64);
    vals[k] = v;
  }
  if (lane == 0) {
#pragma unroll
    for (int k = 0; k < 15; ++k) red[w][k] = vals[k];
  }
  __syncthreads();
  if (tid == 0) {
    float* FP = ws + WS_FPART + ((b << 4) + chunk) * 15;
#pragma unroll
    for (int k = 0; k < 15; ++k) FP[k] = red[0][k] + red[1][k] + red[2][k] + red[3][k];
  }
}

__global__ void __launch_bounds__(256) k_fsolve(float* __restrict__ ws, float* __restrict__ out) {
  const int t = threadIdx.x;
  const int b = t >> 5;
  const int j = t & 31;
  float acc[15];
  if (j < 16) {
    const float* F = ws + WS_FPART + ((b << 4) + j) * 15;
#pragma unroll
    for (int k = 0; k < 15; ++k) acc[k] = F[k];
  } else {
#pragma unroll
    for (int k = 0; k < 15; ++k) acc[k] = 0.0f;
  }
#pragma unroll
  for (int k = 0; k < 15; ++k) {
    float v = acc[k];
    v += __shfl_xor(v, 16, 64);
    v += __shfl_xor(v, 8, 64);
    v += __shfl_xor(v, 4, 64);
    v += __shfl_xor(v, 2, 64);
    v += __shfl_xor(v, 1, 64);
    acc[k] = v;
  }
  if (j == 0) {
    double Ss[3] = {acc[0], acc[1], acc[2]};
    double Sc[3] = {acc[3], acc[4], acc[5]};
    double Pm[9];
#pragma unroll
    for (int k = 0; k < 9; ++k) Pm[k] = acc[6 + k];
    double R[3][3], tr[3];
    kabsch3(Pm, Ss, Sc, R, tr);
#pragma unroll
    for (int i = 0; i < 3; ++i) {
#pragma unroll
      for (int jj = 0; jj < 3; ++jj) {
        out[196608 + b * 9 + i * 3 + jj] = (float)R[i][jj];       // rotation_ab
        out[196704 + b * 9 + i * 3 + jj] = (float)R[jj][i];       // rotation_ba = R^T
      }
      out[196680 + b * 3 + i] = (float)tr[i];                     // translation_ab
      out[196776 + b * 3 + i] =
          (float)(-(R[0][i] * tr[0] + R[1][i] * tr[1] + R[2][i] * tr[2]));  // -R^T t
    }
  }
}

extern "C" void kernel_launch(void* const* d_in, const int* in_sizes, int n_in,
                              void* d_out, int out_size, void* d_ws, size_t ws_size,
                              hipStream_t stream) {
  (void)in_sizes; (void)n_in; (void)out_size; (void)ws_size;
  const float* srcInit = (const float*)d_in[0];
  const float* dst = (const float*)d_in[1];
  float* out = (float*)d_out;
  float* ws = (float*)d_ws;

  k_prep<<<256, 256, 0, stream>>>(srcInit, dst, ws, out);
  for (int it = 0; it < 10; ++it)
    k_nn<<<dim3(64, 8), 512, 0, stream>>>(ws, it);
  k_final<<<dim3(16, 8), 256, 0, stream>>>(srcInit, ws, out);
  k_fsolve<<<1, 256, 0, stream>>>(ws, out);
}

// Round 10
// 114.028 us; speedup vs baseline: 2.0457x; 1.6636x over previous
//
#include <hip/hip_runtime.h>
#include <math.h>

#define NPTS 4096
#define NBATCH 8

// ws layout (float offsets)
#define WS_SRC    0          // [8][3][4096]                 = 98304
#define WS_PACKED 98304      // [8][4096] float4             = 131072 floats
#define WS_PART   229376     // 2 x [512][16] ping-pong      = 16384 floats
#define WS_FPART  229376     // overlaps PART slot0 (dead by k_final)
#define WS_STATE  245760     // slot0 {prev_err,done} slot1 {prev_err,done}
#define WS_PVAL   245764     // 2 x [512] ping-pong val partials (contiguous)

__device__ __forceinline__ void jrot(double A[3][3], double V[3][3], int p, int q) {
  double apq = A[p][q];
  if (fabs(apq) > 0.0) {
    double tau = (A[q][q] - A[p][p]) / (2.0 * apq);
    double tt = (tau >= 0.0 ? 1.0 : -1.0) / (fabs(tau) + sqrt(1.0 + tau * tau));
    double c = 1.0 / sqrt(1.0 + tt * tt);
    double s = tt * c;
#pragma unroll
    for (int k = 0; k < 3; ++k) { double akp = A[k][p], akq = A[k][q]; A[k][p] = c*akp - s*akq; A[k][q] = s*akp + c*akq; }
#pragma unroll
    for (int k = 0; k < 3; ++k) { double apk = A[p][k], aqk = A[q][k]; A[p][k] = c*apk - s*aqk; A[q][k] = s*apk + c*aqk; }
#pragma unroll
    for (int k = 0; k < 3; ++k) { double vkp = V[k][p], vkq = V[k][q]; V[k][p] = c*vkp - s*vkq; V[k][q] = s*vkp + c*vkq; }
  }
}

// P = sum s_i c_j (row-major 9), Ss = sum s, Sc = sum c, n = 4096.
// Kabsch R (src->corr), t = cbar - R sbar; matches svd+reflection-fix reference.
__device__ void kabsch3(const double P[9], const double Ss[3], const double Sc[3],
                        double R[3][3], double t[3]) {
  const double invn = 1.0 / 4096.0;
  double sb[3], cb[3];
#pragma unroll
  for (int i = 0; i < 3; ++i) { sb[i] = Ss[i] * invn; cb[i] = Sc[i] * invn; }
  double H[3][3];
#pragma unroll
  for (int i = 0; i < 3; ++i)
#pragma unroll
    for (int j = 0; j < 3; ++j)
      H[i][j] = P[i * 3 + j] - Ss[i] * cb[j];

  double A[3][3];
  double V[3][3] = {{1,0,0},{0,1,0},{0,0,1}};
#pragma unroll
  for (int i = 0; i < 3; ++i)
#pragma unroll
    for (int j = 0; j < 3; ++j)
      A[i][j] = H[0][i]*H[0][j] + H[1][i]*H[1][j] + H[2][i]*H[2][j];

  for (int sw = 0; sw < 6; ++sw) {
    jrot(A, V, 0, 1);
    jrot(A, V, 0, 2);
    jrot(A, V, 1, 2);
  }
  double l0 = A[0][0], l1 = A[1][1], l2 = A[2][2];
  if (l0 < l1) {
    double tm = l0; l0 = l1; l1 = tm;
#pragma unroll
    for (int k = 0; k < 3; ++k) { double tv = V[k][0]; V[k][0] = V[k][1]; V[k][1] = tv; }
  }
  if (l0 < l2) {
    double tm = l0; l0 = l2; l2 = tm;
#pragma unroll
    for (int k = 0; k < 3; ++k) { double tv = V[k][0]; V[k][0] = V[k][2]; V[k][2] = tv; }
  }
  if (l1 < l2) {
    double tm = l1; l1 = l2; l2 = tm;
#pragma unroll
    for (int k = 0; k < 3; ++k) { double tv = V[k][1]; V[k][1] = V[k][2]; V[k][2] = tv; }
  }
  double U[3][3];
  double nrm0 = 0.0, nrm2 = 0.0;
#pragma unroll
  for (int k = 0; k < 3; ++k) {
    double ux = H[0][0]*V[0][k] + H[0][1]*V[1][k] + H[0][2]*V[2][k];
    double uy = H[1][0]*V[0][k] + H[1][1]*V[1][k] + H[1][2]*V[2][k];
    double uz = H[2][0]*V[0][k] + H[2][1]*V[1][k] + H[2][2]*V[2][k];
    double nn2 = sqrt(ux*ux + uy*uy + uz*uz);
    if (k == 0) nrm0 = nn2;
    if (k == 2) nrm2 = nn2;
    double inv = (nn2 > 0.0) ? 1.0 / nn2 : 0.0;
    U[0][k] = ux * inv; U[1][k] = uy * inv; U[2][k] = uz * inv;
  }
  if (nrm0 <= 1e-30) {
#pragma unroll
    for (int i = 0; i < 3; ++i)
#pragma unroll
      for (int j = 0; j < 3; ++j)
        R[i][j] = (i == j) ? 1.0 : 0.0;
  } else {
    if (nrm2 <= nrm0 * 1e-12) {
      double cx = U[1][0]*U[2][1] - U[2][0]*U[1][1];
      double cy = U[2][0]*U[0][1] - U[0][0]*U[2][1];
      double cz = U[0][0]*U[1][1] - U[1][0]*U[0][1];
      double cn = sqrt(cx*cx + cy*cy + cz*cz);
      double inv = (cn > 0.0) ? 1.0 / cn : 0.0;
      U[0][2] = cx * inv; U[1][2] = cy * inv; U[2][2] = cz * inv;
    }
#pragma unroll
    for (int i = 0; i < 3; ++i)
#pragma unroll
      for (int j = 0; j < 3; ++j)
        R[i][j] = V[i][0]*U[j][0] + V[i][1]*U[j][1] + V[i][2]*U[j][2];
    double det =
        R[0][0]*(R[1][1]*R[2][2] - R[1][2]*R[2][1])
      - R[0][1]*(R[1][0]*R[2][2] - R[1][2]*R[2][0])
      + R[0][2]*(R[1][0]*R[2][1] - R[1][1]*R[2][0]);
    if (det < 0.0) {
#pragma unroll
      for (int i = 0; i < 3; ++i)
#pragma unroll
        for (int j = 0; j < 3; ++j)
          R[i][j] -= 2.0 * V[i][2] * U[j][2];
    }
  }
#pragma unroll
  for (int i = 0; i < 3; ++i)
    t[i] = cb[i] - (R[i][0]*sb[0] + R[i][1]*sb[1] + R[i][2]*sb[2]);
}

// Old-style block-redundant solve over all 8 batches (used only by k_final,
// blockDim >= 256). Caller must __syncthreads() after.
__device__ __forceinline__ void solve_head(const float* __restrict__ PT,
                                           float s_RT[8][12], float s_val[8],
                                           int tid) {
  if (tid < 256) {
    const int sb2 = tid >> 5;
    const int j = tid & 31;
    float acc[16];
    const float* P0 = PT + ((sb2 << 6) + j) * 16;
    const float* P1 = P0 + 32 * 16;
#pragma unroll
    for (int k = 0; k < 16; ++k) acc[k] = P0[k] + P1[k];
#pragma unroll
    for (int k = 0; k < 16; ++k) {
      float v = acc[k];
      v += __shfl_xor(v, 16, 64);
      v += __shfl_xor(v, 8, 64);
      v += __shfl_xor(v, 4, 64);
      v += __shfl_xor(v, 2, 64);
      v += __shfl_xor(v, 1, 64);
      acc[k] = v;
    }
    if (j == 0) {
      s_val[sb2] = acc[0];
      double Ss[3] = {acc[1], acc[2], acc[3]};
      double Sc[3] = {acc[4], acc[5], acc[6]};
      double Pm[9];
#pragma unroll
      for (int k = 0; k < 9; ++k) Pm[k] = acc[7 + k];
      double R[3][3], tr[3];
      kabsch3(Pm, Ss, Sc, R, tr);
#pragma unroll
      for (int i = 0; i < 3; ++i)
#pragma unroll
        for (int jj = 0; jj < 3; ++jj) s_RT[sb2][i * 3 + jj] = (float)R[i][jj];
#pragma unroll
      for (int i = 0; i < 3; ++i) s_RT[sb2][9 + i] = (float)tr[i];
    }
  }
}

__global__ void k_prep(const float* __restrict__ srcInit, const float* __restrict__ dst,
                       float* __restrict__ ws, float* __restrict__ out) {
  const int gid = blockIdx.x * blockDim.x + threadIdx.x;
  const int stride = gridDim.x * blockDim.x;
  float4* packed = (float4*)(ws + WS_PACKED);
  for (int i = gid; i < NBATCH * NPTS; i += stride) {
    const int b = i >> 12, m = i & (NPTS - 1);
    const float dx = dst[b * 3 * NPTS + m];
    const float dy = dst[b * 3 * NPTS + NPTS + m];
    const float dz = dst[b * 3 * NPTS + 2 * NPTS + m];
    const float nyy = -fmaf(dx, dx, fmaf(dy, dy, dz * dz));
    packed[i] = make_float4(dx, dy, dz, nyy);
  }
  const float4* s4 = (const float4*)srcInit;
  float4* w4 = (float4*)(ws + WS_SRC);
  float4* o4 = (float4*)out;
  for (int i = gid; i < (NBATCH * 3 * NPTS) / 4; i += stride) {
    float4 v = s4[i];
    w4[i] = v;
    o4[i] = v;  // output 0: srcInit pass-through
  }
  if (gid == 0) {
    ws[WS_STATE + 0] = 0.0f;  // slot0 prev_err (= err_{-1})
    ws[WS_STATE + 1] = 0.0f;  // slot0 done_{-1}
  }
}

// grid (64,8) x 512 thr, launched 10x with it=0..9. R9 structure; scan
// addresses made provably wave-uniform (readfirstlane) with packed passed as
// a separate restrict pointer so the compiler can select scalar (SMEM) loads
// off the VALU/VMEM critical path. max3-friendly reduction tree.
__global__ void __launch_bounds__(512, 4) k_nn(float* __restrict__ ws,
                                               const float4* __restrict__ packed_all,
                                               int it) {
  const int b = blockIdx.y;
  const int chunk = blockIdx.x;
  const int tid = threadIdx.x;
  const int slice = tid >> 6;
  const int pidx = tid & 63;
  const int n = (chunk << 6) + pidx;

  __shared__ float rv[8][64];
  __shared__ int ri[8][64];
  __shared__ float s_RT[12];
  __shared__ float s_done_new;

  float* state = ws + WS_STATE;
  float* src = ws + WS_SRC;
  const int sbase = b * 3 * NPTS + n;
  float sx = src[sbase];
  float sy = src[sbase + NPTS];
  float sz = src[sbase + 2 * NPTS];

  bool skip_scan = false;
  if (it > 0) {
    const int ps = (it - 1) & 1;
    const float prev_err = state[ps * 2 + 0];   // err_{it-2}
    const float done_prev = state[ps * 2 + 1];  // done_{it-2}
    if (done_prev != 0.0f) {
      // fully frozen: copy state forward, touch nothing else
      if (blockIdx.x == 0 && blockIdx.y == 0 && tid == 0) {
        state[(it & 1) * 2 + 0] = prev_err;
        state[(it & 1) * 2 + 1] = 1.0f;
      }
      return;
    }
    // --- lean per-batch solve of fit_{it-1} ---
    if (tid < 64) {
      // batch b's 64 partial rows: lane tid reads row (b<<6)+tid (64 B)
      const float* row = ws + WS_PART + ps * 8192 + ((b << 6) + tid) * 16;
      const float4 r0 = *(const float4*)(row + 0);
      const float4 r1 = *(const float4*)(row + 4);
      const float4 r2 = *(const float4*)(row + 8);
      const float4 r3 = *(const float4*)(row + 12);
      float a[16] = {r0.x, r0.y, r0.z, r0.w, r1.x, r1.y, r1.z, r1.w,
                     r2.x, r2.y, r2.z, r2.w, r3.x, r3.y, r3.z, r3.w};
#pragma unroll
      for (int k = 1; k < 16; ++k) {  // a[0]=val unused here
        float v = a[k];
        v += __shfl_xor(v, 32, 64);
        v += __shfl_xor(v, 16, 64);
        v += __shfl_xor(v, 8, 64);
        v += __shfl_xor(v, 4, 64);
        v += __shfl_xor(v, 2, 64);
        v += __shfl_xor(v, 1, 64);
        a[k] = v;
      }
      if (tid == 0) {
        double Ss[3] = {a[1], a[2], a[3]};
        double Sc[3] = {a[4], a[5], a[6]};
        double Pm[9];
#pragma unroll
        for (int k = 0; k < 9; ++k) Pm[k] = a[7 + k];
        double R[3][3], tr[3];
        kabsch3(Pm, Ss, Sc, R, tr);
#pragma unroll
        for (int i = 0; i < 3; ++i)
#pragma unroll
          for (int jj = 0; jj < 3; ++jj) s_RT[i * 3 + jj] = (float)R[i][jj];
#pragma unroll
        for (int i = 0; i < 3; ++i) s_RT[9 + i] = (float)tr[i];
      }
    } else if (tid < 128) {
      // err: contiguous 512-float PVAL, lane l reads l + 64*j (coalesced)
      const int l = tid - 64;
      const float* PV = ws + WS_PVAL + ps * 512;
      float s = 0.0f;
#pragma unroll
      for (int j = 0; j < 8; ++j) s += PV[l + (j << 6)];
      s += __shfl_xor(s, 32, 64);
      s += __shfl_xor(s, 16, 64);
      s += __shfl_xor(s, 8, 64);
      s += __shfl_xor(s, 4, 64);
      s += __shfl_xor(s, 2, 64);
      s += __shfl_xor(s, 1, 64);
      if (tid == 64) {
        const float err = s * (1.0f / 32768.0f);  // err_{it-1}
        const float dn = (fabsf(prev_err - err) < 0.001f) ? 1.0f : 0.0f;
        s_done_new = dn;
        if (blockIdx.x == 0 && blockIdx.y == 0) {
          state[(it & 1) * 2 + 0] = err;
          state[(it & 1) * 2 + 1] = dn;
        }
      }
    }
    __syncthreads();  // publish s_RT / s_done_new; all src reads above done
    // apply R_{it-1},t (done_{it-2}==0 here)
    const float* RT = s_RT;
    const float nx = fmaf(RT[0], sx, fmaf(RT[1], sy, fmaf(RT[2], sz, RT[9])));
    const float ny = fmaf(RT[3], sx, fmaf(RT[4], sy, fmaf(RT[5], sz, RT[10])));
    const float nz = fmaf(RT[6], sx, fmaf(RT[7], sy, fmaf(RT[8], sz, RT[11])));
    sx = nx; sy = ny; sz = nz;
    if (slice == 0) {  // safe: all reads completed before the barrier
      src[sbase] = sx;
      src[sbase + NPTS] = sy;
      src[sbase + 2 * NPTS] = sz;
    }
    skip_scan = (s_done_new != 0.0f);
  }

  if (skip_scan) return;  // uniform across grid

  const float4* __restrict__ packed = packed_all + b * NPTS;
  const float s2x = 2.0f * sx, s2y = 2.0f * sy, s2z = 2.0f * sz;
  // slice is wave-uniform: readfirstlane makes it provably SGPR so the
  // broadcast loads below can select the scalar (SMEM) path.
  const int uslice = __builtin_amdgcn_readfirstlane(slice);
  const int m0 = uslice << 9;
  const float4* __restrict__ bp = packed + m0;

  float best = -3.0e38f;
  int gwin = 0;
#pragma unroll 2
  for (int g = 0; g < 64; ++g) {
    const float4 d0 = bp[(g << 3) + 0];
    const float4 d1 = bp[(g << 3) + 1];
    const float4 d2 = bp[(g << 3) + 2];
    const float4 d3 = bp[(g << 3) + 3];
    const float4 d4 = bp[(g << 3) + 4];
    const float4 d5 = bp[(g << 3) + 5];
    const float4 d6 = bp[(g << 3) + 6];
    const float4 d7 = bp[(g << 3) + 7];
    const float p0 = fmaf(s2x, d0.x, fmaf(s2y, d0.y, fmaf(s2z, d0.z, d0.w)));
    const float p1 = fmaf(s2x, d1.x, fmaf(s2y, d1.y, fmaf(s2z, d1.z, d1.w)));
    const float p2 = fmaf(s2x, d2.x, fmaf(s2y, d2.y, fmaf(s2z, d2.z, d2.w)));
    const float p3 = fmaf(s2x, d3.x, fmaf(s2y, d3.y, fmaf(s2z, d3.z, d3.w)));
    const float p4 = fmaf(s2x, d4.x, fmaf(s2y, d4.y, fmaf(s2z, d4.z, d4.w)));
    const float p5 = fmaf(s2x, d5.x, fmaf(s2y, d5.y, fmaf(s2z, d5.z, d5.w)));
    const float p6 = fmaf(s2x, d6.x, fmaf(s2y, d6.y, fmaf(s2z, d6.z, d6.w)));
    const float p7 = fmaf(s2x, d7.x, fmaf(s2y, d7.y, fmaf(s2z, d7.z, d7.w)));
    // max3-friendly tree (v_max3_f32 fusion): 4 instrs instead of 7
    const float t0 = fmaxf(fmaxf(p0, p1), p2);
    const float t1 = fmaxf(fmaxf(p3, p4), p5);
    const float t2 = fmaxf(p6, p7);
    const float gm = fmaxf(fmaxf(t0, t1), t2);
    // strict > with ascending g: first group attaining the max wins.
    if (gm > best) { best = gm; gwin = g; }
  }
  // Exact first-max index within winning group (bit-identical recompute,
  // descending j so smallest index wins). gwin is per-lane: vector loads.
  const int gb = m0 + (gwin << 3);
  const float4* __restrict__ gp = packed + gb;
  int bi = gb;
#pragma unroll
  for (int j = 7; j >= 0; --j) {
    const float4 d = gp[j];
    const float p = fmaf(s2x, d.x, fmaf(s2y, d.y, fmaf(s2z, d.z, d.w)));
    if (p == best) bi = gb + j;
  }

  rv[slice][pidx] = best;
  ri[slice][pidx] = bi;
  __syncthreads();

  if (slice == 0) {
    float bv = rv[0][pidx];
    int bidx = ri[0][pidx];
#pragma unroll
    for (int s = 1; s < 8; ++s) {
      const float v = rv[s][pidx];
      if (v > bv) { bv = v; bidx = ri[s][pidx]; }  // ascending slice: first max
    }
    const float4 c = packed[bidx];
    const float xx = fmaf(sx, sx, fmaf(sy, sy, sz * sz));
    float vals[16];
    vals[0] = bv - xx;          // val = max(2 s.d - yy) - xx
    vals[1] = sx;  vals[2] = sy;  vals[3] = sz;
    vals[4] = c.x; vals[5] = c.y; vals[6] = c.z;
    vals[7]  = sx * c.x; vals[8]  = sx * c.y; vals[9]  = sx * c.z;
    vals[10] = sy * c.x; vals[11] = sy * c.y; vals[12] = sy * c.z;
    vals[13] = sz * c.x; vals[14] = sz * c.y; vals[15] = sz * c.z;
#pragma unroll
    for (int k = 0; k < 16; ++k) {
      float v = vals[k];
#pragma unroll
      for (int off = 32; off >= 1; off >>= 1) v += __shfl_xor(v, off, 64);
      vals[k] = v;
    }
    if (pidx == 0) {
      float* Pp = ws + WS_PART + (it & 1) * 8192 + ((b << 6) + chunk) * 16;
#pragma unroll
      for (int k = 0; k < 16; ++k) Pp[k] = vals[k];
      ws[WS_PVAL + (it & 1) * 512 + (b << 6) + chunk] = vals[0];
    }
  }
}

// grid (16,8) x 256 thr (= dispatch 10): block-redundant solve of fit_9 from
// partials slot 1 (gated on done_8 in state slot 1), apply, write final src,
// emit partials for the final Kabsch.
__global__ void __launch_bounds__(256, 4) k_final(const float* __restrict__ srcInit,
                                                  float* __restrict__ ws,
                                                  float* __restrict__ out) {
  const int b = blockIdx.y;
  const int chunk = blockIdx.x;
  const int tid = threadIdx.x;
  const int n = (chunk << 8) + tid;
  __shared__ float red[4][15];
  __shared__ float s_RT[8][12];
  __shared__ float s_val[8];
  float* state = ws + WS_STATE;
  const float done8 = state[2 + 1];  // slot1.done (written by dispatch it=9)
  const int sbase = b * 3 * NPTS + n;
  float sx = ws[WS_SRC + sbase];
  float sy = ws[WS_SRC + sbase + NPTS];
  float sz = ws[WS_SRC + sbase + 2 * NPTS];
  if (done8 == 0.0f) {
    solve_head(ws + WS_PART + 8192, s_RT, s_val, tid);  // fit_9 from slot1
    __syncthreads();
    const float* RT = s_RT[b];
    const float nx = fmaf(RT[0], sx, fmaf(RT[1], sy, fmaf(RT[2], sz, RT[9])));
    const float ny = fmaf(RT[3], sx, fmaf(RT[4], sy, fmaf(RT[5], sz, RT[10])));
    const float nz = fmaf(RT[6], sx, fmaf(RT[7], sy, fmaf(RT[8], sz, RT[11])));
    sx = nx; sy = ny; sz = nz;
  }
  out[98304 + sbase] = sx;
  out[98304 + sbase + NPTS] = sy;
  out[98304 + sbase + 2 * NPTS] = sz;

  const float ax = srcInit[sbase];
  const float ay = srcInit[sbase + NPTS];
  const float az = srcInit[sbase + 2 * NPTS];
  float vals[15];
  vals[0] = ax; vals[1] = ay; vals[2] = az;
  vals[3] = sx; vals[4] = sy; vals[5] = sz;
  vals[6]  = ax * sx; vals[7]  = ax * sy; vals[8]  = ax * sz;
  vals[9]  = ay * sx; vals[10] = ay * sy; vals[11] = ay * sz;
  vals[12] = az * sx; vals[13] = az * sy; vals[14] = az * sz;
  const int w = tid >> 6, lane = tid & 63;
#pragma unroll
  for (int k = 0; k < 15; ++k) {
    float v = vals[k];
#pragma unroll
    for (int off = 32; off >= 1; off >>= 1) v += __shfl_xor(v, off, 64);
    vals[k] = v;
  }
  if (lane == 0) {
#pragma unroll
    for (int k = 0; k < 15; ++k) red[w][k] = vals[k];
  }
  __syncthreads();
  if (tid == 0) {
    float* FP = ws + WS_FPART + ((b << 4) + chunk) * 15;
#pragma unroll
    for (int k = 0; k < 15; ++k) FP[k] = red[0][k] + red[1][k] + red[2][k] + red[3][k];
  }
}

__global__ void __launch_bounds__(256) k_fsolve(float* __restrict__ ws, float* __restrict__ out) {
  const int t = threadIdx.x;
  const int b = t >> 5;
  const int j = t & 31;
  float acc[15];
  if (j < 16) {
    const float* F = ws + WS_FPART + ((b << 4) + j) * 15;
#pragma unroll
    for (int k = 0; k < 15; ++k) acc[k] = F[k];
  } else {
#pragma unroll
    for (int k = 0; k < 15; ++k) acc[k] = 0.0f;
  }
#pragma unroll
  for (int k = 0; k < 15; ++k) {
    float v = acc[k];
    v += __shfl_xor(v, 16, 64);
    v += __shfl_xor(v, 8, 64);
    v += __shfl_xor(v, 4, 64);
    v += __shfl_xor(v, 2, 64);
    v += __shfl_xor(v, 1, 64);
    acc[k] = v;
  }
  if (j == 0) {
    double Ss[3] = {acc[0], acc[1], acc[2]};
    double Sc[3] = {acc[3], acc[4], acc[5]};
    double Pm[9];
#pragma unroll
    for (int k = 0; k < 9; ++k) Pm[k] = acc[6 + k];
    double R[3][3], tr[3];
    kabsch3(Pm, Ss, Sc, R, tr);
#pragma unroll
    for (int i = 0; i < 3; ++i) {
#pragma unroll
      for (int jj = 0; jj < 3; ++jj) {
        out[196608 + b * 9 + i * 3 + jj] = (float)R[i][jj];       // rotation_ab
        out[196704 + b * 9 + i * 3 + jj] = (float)R[jj][i];       // rotation_ba = R^T
      }
      out[196680 + b * 3 + i] = (float)tr[i];                     // translation_ab
      out[196776 + b * 3 + i] =
          (float)(-(R[0][i] * tr[0] + R[1][i] * tr[1] + R[2][i] * tr[2]));  // -R^T t
    }
  }
}

extern "C" void kernel_launch(void* const* d_in, const int* in_sizes, int n_in,
                              void* d_out, int out_size, void* d_ws, size_t ws_size,
                              hipStream_t stream) {
  (void)in_sizes; (void)n_in; (void)out_size; (void)ws_size;
  const float* srcInit = (const float*)d_in[0];
  const float* dst = (const float*)d_in[1];
  float* out = (float*)d_out;
  float* ws = (float*)d_ws;
  const float4* packed_all = (const float4*)(ws + WS_PACKED);

  k_prep<<<256, 256, 0, stream>>>(srcInit, dst, ws, out);
  for (int it = 0; it < 10; ++it)
    k_nn<<<dim3(64, 8), 512, 0, stream>>>(ws, packed_all, it);
  k_final<<<dim3(16, 8), 256, 0, stream>>>(srcInit, ws, out);
  k_fsolve<<<1, 256, 0, stream>>>(ws, out);
}

// Round 11
// 105.912 us; speedup vs baseline: 2.2025x; 1.0766x over previous
//
#include <hip/hip_runtime.h>
#include <math.h>

#define NPTS 4096
#define NBATCH 8

// ws layout (float offsets)
#define WS_SRC    0          // [8][3][4096]                 = 98304
#define WS_PA     98304      // [8][2048] float4 (x0,x1,y0,y1) = 65536
#define WS_PB     163840     // [8][2048] float4 (z0,z1,w0,w1) = 65536
#define WS_PART   229376     // 2 x [512][16] ping-pong      = 16384 floats
#define WS_FPART  229376     // overlaps PART slot0 (dead by k_final)
#define WS_STATE  245760     // slot0 {prev_err,done} slot1 {prev_err,done}
#define WS_PVAL   245764     // 2 x [512] ping-pong val partials (contiguous)

typedef float f2 __attribute__((ext_vector_type(2)));
__device__ __forceinline__ f2 mk2(float a, float b) { f2 r; r.x = a; r.y = b; return r; }
__device__ __forceinline__ f2 f2fma(f2 a, f2 b, f2 c) { return __builtin_elementwise_fma(a, b, c); }
__device__ __forceinline__ f2 f2max(f2 a, f2 b) { return __builtin_elementwise_max(a, b); }

__device__ __forceinline__ void jrot(double A[3][3], double V[3][3], int p, int q) {
  double apq = A[p][q];
  if (fabs(apq) > 0.0) {
    double tau = (A[q][q] - A[p][p]) / (2.0 * apq);
    double tt = (tau >= 0.0 ? 1.0 : -1.0) / (fabs(tau) + sqrt(1.0 + tau * tau));
    double c = 1.0 / sqrt(1.0 + tt * tt);
    double s = tt * c;
#pragma unroll
    for (int k = 0; k < 3; ++k) { double akp = A[k][p], akq = A[k][q]; A[k][p] = c*akp - s*akq; A[k][q] = s*akp + c*akq; }
#pragma unroll
    for (int k = 0; k < 3; ++k) { double apk = A[p][k], aqk = A[q][k]; A[p][k] = c*apk - s*aqk; A[q][k] = s*apk + c*aqk; }
#pragma unroll
    for (int k = 0; k < 3; ++k) { double vkp = V[k][p], vkq = V[k][q]; V[k][p] = c*vkp - s*vkq; V[k][q] = s*vkp + c*vkq; }
  }
}

// P = sum s_i c_j (row-major 9), Ss = sum s, Sc = sum c, n = 4096.
// Kabsch R (src->corr), t = cbar - R sbar; matches svd+reflection-fix reference.
__device__ void kabsch3(const double P[9], const double Ss[3], const double Sc[3],
                        double R[3][3], double t[3]) {
  const double invn = 1.0 / 4096.0;
  double sb[3], cb[3];
#pragma unroll
  for (int i = 0; i < 3; ++i) { sb[i] = Ss[i] * invn; cb[i] = Sc[i] * invn; }
  double H[3][3];
#pragma unroll
  for (int i = 0; i < 3; ++i)
#pragma unroll
    for (int j = 0; j < 3; ++j)
      H[i][j] = P[i * 3 + j] - Ss[i] * cb[j];

  double A[3][3];
  double V[3][3] = {{1,0,0},{0,1,0},{0,0,1}};
#pragma unroll
  for (int i = 0; i < 3; ++i)
#pragma unroll
    for (int j = 0; j < 3; ++j)
      A[i][j] = H[0][i]*H[0][j] + H[1][i]*H[1][j] + H[2][i]*H[2][j];

  for (int sw = 0; sw < 6; ++sw) {
    jrot(A, V, 0, 1);
    jrot(A, V, 0, 2);
    jrot(A, V, 1, 2);
  }
  double l0 = A[0][0], l1 = A[1][1], l2 = A[2][2];
  if (l0 < l1) {
    double tm = l0; l0 = l1; l1 = tm;
#pragma unroll
    for (int k = 0; k < 3; ++k) { double tv = V[k][0]; V[k][0] = V[k][1]; V[k][1] = tv; }
  }
  if (l0 < l2) {
    double tm = l0; l0 = l2; l2 = tm;
#pragma unroll
    for (int k = 0; k < 3; ++k) { double tv = V[k][0]; V[k][0] = V[k][2]; V[k][2] = tv; }
  }
  if (l1 < l2) {
    double tm = l1; l1 = l2; l2 = tm;
#pragma unroll
    for (int k = 0; k < 3; ++k) { double tv = V[k][1]; V[k][1] = V[k][2]; V[k][2] = tv; }
  }
  double U[3][3];
  double nrm0 = 0.0, nrm2 = 0.0;
#pragma unroll
  for (int k = 0; k < 3; ++k) {
    double ux = H[0][0]*V[0][k] + H[0][1]*V[1][k] + H[0][2]*V[2][k];
    double uy = H[1][0]*V[0][k] + H[1][1]*V[1][k] + H[1][2]*V[2][k];
    double uz = H[2][0]*V[0][k] + H[2][1]*V[1][k] + H[2][2]*V[2][k];
    double nn2 = sqrt(ux*ux + uy*uy + uz*uz);
    if (k == 0) nrm0 = nn2;
    if (k == 2) nrm2 = nn2;
    double inv = (nn2 > 0.0) ? 1.0 / nn2 : 0.0;
    U[0][k] = ux * inv; U[1][k] = uy * inv; U[2][k] = uz * inv;
  }
  if (nrm0 <= 1e-30) {
#pragma unroll
    for (int i = 0; i < 3; ++i)
#pragma unroll
      for (int j = 0; j < 3; ++j)
        R[i][j] = (i == j) ? 1.0 : 0.0;
  } else {
    if (nrm2 <= nrm0 * 1e-12) {
      double cx = U[1][0]*U[2][1] - U[2][0]*U[1][1];
      double cy = U[2][0]*U[0][1] - U[0][0]*U[2][1];
      double cz = U[0][0]*U[1][1] - U[1][0]*U[0][1];
      double cn = sqrt(cx*cx + cy*cy + cz*cz);
      double inv = (cn > 0.0) ? 1.0 / cn : 0.0;
      U[0][2] = cx * inv; U[1][2] = cy * inv; U[2][2] = cz * inv;
    }
#pragma unroll
    for (int i = 0; i < 3; ++i)
#pragma unroll
      for (int j = 0; j < 3; ++j)
        R[i][j] = V[i][0]*U[j][0] + V[i][1]*U[j][1] + V[i][2]*U[j][2];
    double det =
        R[0][0]*(R[1][1]*R[2][2] - R[1][2]*R[2][1])
      - R[0][1]*(R[1][0]*R[2][2] - R[1][2]*R[2][0])
      + R[0][2]*(R[1][0]*R[2][1] - R[1][1]*R[2][0]);
    if (det < 0.0) {
#pragma unroll
      for (int i = 0; i < 3; ++i)
#pragma unroll
        for (int j = 0; j < 3; ++j)
          R[i][j] -= 2.0 * V[i][2] * U[j][2];
    }
  }
#pragma unroll
  for (int i = 0; i < 3; ++i)
    t[i] = cb[i] - (R[i][0]*sb[0] + R[i][1]*sb[1] + R[i][2]*sb[2]);
}

// Old-style block-redundant solve over all 8 batches (used only by k_final,
// blockDim >= 256). Caller must __syncthreads() after.
__device__ __forceinline__ void solve_head(const float* __restrict__ PT,
                                           float s_RT[8][12], float s_val[8],
                                           int tid) {
  if (tid < 256) {
    const int sb2 = tid >> 5;
    const int j = tid & 31;
    float acc[16];
    const float* P0 = PT + ((sb2 << 6) + j) * 16;
    const float* P1 = P0 + 32 * 16;
#pragma unroll
    for (int k = 0; k < 16; ++k) acc[k] = P0[k] + P1[k];
#pragma unroll
    for (int k = 0; k < 16; ++k) {
      float v = acc[k];
      v += __shfl_xor(v, 16, 64);
      v += __shfl_xor(v, 8, 64);
      v += __shfl_xor(v, 4, 64);
      v += __shfl_xor(v, 2, 64);
      v += __shfl_xor(v, 1, 64);
      acc[k] = v;
    }
    if (j == 0) {
      s_val[sb2] = acc[0];
      double Ss[3] = {acc[1], acc[2], acc[3]};
      double Sc[3] = {acc[4], acc[5], acc[6]};
      double Pm[9];
#pragma unroll
      for (int k = 0; k < 9; ++k) Pm[k] = acc[7 + k];
      double R[3][3], tr[3];
      kabsch3(Pm, Ss, Sc, R, tr);
#pragma unroll
      for (int i = 0; i < 3; ++i)
#pragma unroll
        for (int jj = 0; jj < 3; ++jj) s_RT[sb2][i * 3 + jj] = (float)R[i][jj];
#pragma unroll
      for (int i = 0; i < 3; ++i) s_RT[sb2][9 + i] = (float)tr[i];
    }
  }
}

__global__ void k_prep(const float* __restrict__ srcInit, const float* __restrict__ dst,
                       float* __restrict__ ws, float* __restrict__ out) {
  const int gid = blockIdx.x * blockDim.x + threadIdx.x;
  const int stride = gridDim.x * blockDim.x;
  float4* PA = (float4*)(ws + WS_PA);
  float4* PB = (float4*)(ws + WS_PB);
  for (int i = gid; i < NBATCH * 2048; i += stride) {
    const int b = i >> 11, p = i & 2047, m0 = p << 1;
    const int base = b * 3 * NPTS;
    const float2 X = *(const float2*)(dst + base + m0);
    const float2 Y = *(const float2*)(dst + base + NPTS + m0);
    const float2 Z = *(const float2*)(dst + base + 2 * NPTS + m0);
    const float w0 = -fmaf(X.x, X.x, fmaf(Y.x, Y.x, Z.x * Z.x));
    const float w1 = -fmaf(X.y, X.y, fmaf(Y.y, Y.y, Z.y * Z.y));
    PA[i] = make_float4(X.x, X.y, Y.x, Y.y);
    PB[i] = make_float4(Z.x, Z.y, w0, w1);
  }
  const float4* s4 = (const float4*)srcInit;
  float4* w4 = (float4*)(ws + WS_SRC);
  float4* o4 = (float4*)out;
  for (int i = gid; i < (NBATCH * 3 * NPTS) / 4; i += stride) {
    float4 v = s4[i];
    w4[i] = v;
    o4[i] = v;  // output 0: srcInit pass-through
  }
  if (gid == 0) {
    ws[WS_STATE + 0] = 0.0f;  // slot0 prev_err (= err_{-1})
    ws[WS_STATE + 1] = 0.0f;  // slot0 done_{-1}
  }
}

// grid (64,8) x 512 thr, launched 10x with it=0..9. R10 structure (lean
// per-batch solve head, SMEM scan via readfirstlane-uniform bases), with the
// scan math in packed-fp32 (v_pk_fma / v_pk_max, 2 points per instruction).
__global__ void __launch_bounds__(512, 4) k_nn(float* __restrict__ ws,
                                               const float4* __restrict__ PA_all,
                                               const float4* __restrict__ PB_all,
                                               int it) {
  const int b = blockIdx.y;
  const int chunk = blockIdx.x;
  const int tid = threadIdx.x;
  const int slice = tid >> 6;
  const int pidx = tid & 63;
  const int n = (chunk << 6) + pidx;

  __shared__ float rv[8][64];
  __shared__ int ri[8][64];
  __shared__ float s_RT[12];
  __shared__ float s_done_new;

  float* state = ws + WS_STATE;
  float* src = ws + WS_SRC;
  const int sbase = b * 3 * NPTS + n;
  float sx = src[sbase];
  float sy = src[sbase + NPTS];
  float sz = src[sbase + 2 * NPTS];

  bool skip_scan = false;
  if (it > 0) {
    const int ps = (it - 1) & 1;
    const float prev_err = state[ps * 2 + 0];   // err_{it-2}
    const float done_prev = state[ps * 2 + 1];  // done_{it-2}
    if (done_prev != 0.0f) {
      // fully frozen: copy state forward, touch nothing else
      if (blockIdx.x == 0 && blockIdx.y == 0 && tid == 0) {
        state[(it & 1) * 2 + 0] = prev_err;
        state[(it & 1) * 2 + 1] = 1.0f;
      }
      return;
    }
    // --- lean per-batch solve of fit_{it-1} ---
    if (tid < 64) {
      // batch b's 64 partial rows: lane tid reads row (b<<6)+tid (64 B)
      const float* row = ws + WS_PART + ps * 8192 + ((b << 6) + tid) * 16;
      const float4 r0 = *(const float4*)(row + 0);
      const float4 r1 = *(const float4*)(row + 4);
      const float4 r2 = *(const float4*)(row + 8);
      const float4 r3 = *(const float4*)(row + 12);
      float a[16] = {r0.x, r0.y, r0.z, r0.w, r1.x, r1.y, r1.z, r1.w,
                     r2.x, r2.y, r2.z, r2.w, r3.x, r3.y, r3.z, r3.w};
#pragma unroll
      for (int k = 1; k < 16; ++k) {  // a[0]=val unused here
        float v = a[k];
        v += __shfl_xor(v, 32, 64);
        v += __shfl_xor(v, 16, 64);
        v += __shfl_xor(v, 8, 64);
        v += __shfl_xor(v, 4, 64);
        v += __shfl_xor(v, 2, 64);
        v += __shfl_xor(v, 1, 64);
        a[k] = v;
      }
      if (tid == 0) {
        double Ss[3] = {a[1], a[2], a[3]};
        double Sc[3] = {a[4], a[5], a[6]};
        double Pm[9];
#pragma unroll
        for (int k = 0; k < 9; ++k) Pm[k] = a[7 + k];
        double R[3][3], tr[3];
        kabsch3(Pm, Ss, Sc, R, tr);
#pragma unroll
        for (int i = 0; i < 3; ++i)
#pragma unroll
          for (int jj = 0; jj < 3; ++jj) s_RT[i * 3 + jj] = (float)R[i][jj];
#pragma unroll
        for (int i = 0; i < 3; ++i) s_RT[9 + i] = (float)tr[i];
      }
    } else if (tid < 128) {
      // err: contiguous 512-float PVAL, lane l reads l + 64*j (coalesced)
      const int l = tid - 64;
      const float* PV = ws + WS_PVAL + ps * 512;
      float s = 0.0f;
#pragma unroll
      for (int j = 0; j < 8; ++j) s += PV[l + (j << 6)];
      s += __shfl_xor(s, 32, 64);
      s += __shfl_xor(s, 16, 64);
      s += __shfl_xor(s, 8, 64);
      s += __shfl_xor(s, 4, 64);
      s += __shfl_xor(s, 2, 64);
      s += __shfl_xor(s, 1, 64);
      if (tid == 64) {
        const float err = s * (1.0f / 32768.0f);  // err_{it-1}
        const float dn = (fabsf(prev_err - err) < 0.001f) ? 1.0f : 0.0f;
        s_done_new = dn;
        if (blockIdx.x == 0 && blockIdx.y == 0) {
          state[(it & 1) * 2 + 0] = err;
          state[(it & 1) * 2 + 1] = dn;
        }
      }
    }
    __syncthreads();  // publish s_RT / s_done_new; all src reads above done
    // apply R_{it-1},t (done_{it-2}==0 here)
    const float* RT = s_RT;
    const float nx = fmaf(RT[0], sx, fmaf(RT[1], sy, fmaf(RT[2], sz, RT[9])));
    const float ny = fmaf(RT[3], sx, fmaf(RT[4], sy, fmaf(RT[5], sz, RT[10])));
    const float nz = fmaf(RT[6], sx, fmaf(RT[7], sy, fmaf(RT[8], sz, RT[11])));
    sx = nx; sy = ny; sz = nz;
    if (slice == 0) {  // safe: all reads completed before the barrier
      src[sbase] = sx;
      src[sbase + NPTS] = sy;
      src[sbase + 2 * NPTS] = sz;
    }
    skip_scan = (s_done_new != 0.0f);
  }

  if (skip_scan) return;  // uniform across grid

  // slice is wave-uniform: readfirstlane makes it provably SGPR so the
  // broadcast loads below can select the scalar (SMEM) path.
  const int uslice = __builtin_amdgcn_readfirstlane(slice);
  const float4* __restrict__ PAb = PA_all + b * 2048 + (uslice << 8);
  const float4* __restrict__ PBb = PB_all + b * 2048 + (uslice << 8);
  const float s2x = 2.0f * sx, s2y = 2.0f * sy, s2z = 2.0f * sz;
  const f2 s2x2 = mk2(s2x, s2x), s2y2 = mk2(s2y, s2y), s2z2 = mk2(s2z, s2z);

  float best = -3.0e38f;
  int gwin = 0;
#pragma unroll 2
  for (int g = 0; g < 64; ++g) {
    const float4 a0 = PAb[(g << 2) + 0];
    const float4 a1 = PAb[(g << 2) + 1];
    const float4 a2 = PAb[(g << 2) + 2];
    const float4 a3 = PAb[(g << 2) + 3];
    const float4 b0 = PBb[(g << 2) + 0];
    const float4 b1 = PBb[(g << 2) + 1];
    const float4 b2 = PBb[(g << 2) + 2];
    const float4 b3 = PBb[(g << 2) + 3];
    const f2 p0 = f2fma(s2x2, mk2(a0.x, a0.y), f2fma(s2y2, mk2(a0.z, a0.w), f2fma(s2z2, mk2(b0.x, b0.y), mk2(b0.z, b0.w))));
    const f2 p1 = f2fma(s2x2, mk2(a1.x, a1.y), f2fma(s2y2, mk2(a1.z, a1.w), f2fma(s2z2, mk2(b1.x, b1.y), mk2(b1.z, b1.w))));
    const f2 p2 = f2fma(s2x2, mk2(a2.x, a2.y), f2fma(s2y2, mk2(a2.z, a2.w), f2fma(s2z2, mk2(b2.x, b2.y), mk2(b2.z, b2.w))));
    const f2 p3 = f2fma(s2x2, mk2(a3.x, a3.y), f2fma(s2y2, mk2(a3.z, a3.w), f2fma(s2z2, mk2(b3.x, b3.y), mk2(b3.z, b3.w))));
    const f2 mm = f2max(f2max(p0, p1), f2max(p2, p3));
    const float gm = fmaxf(mm.x, mm.y);
    // strict > with ascending g: first group attaining the max wins.
    if (gm > best) { best = gm; gwin = g; }
  }
  // Exact first-max index within winning group: scalar recompute is IEEE
  // bit-identical to the pk halves; descending order so smallest index wins.
  int bi = 0;
#pragma unroll
  for (int q = 3; q >= 0; --q) {
    const float4 a = PAb[(gwin << 2) + q];
    const float4 bb = PBb[(gwin << 2) + q];
    const float p1s = fmaf(s2x, a.y, fmaf(s2y, a.w, fmaf(s2z, bb.y, bb.w)));
    const float p0s = fmaf(s2x, a.x, fmaf(s2y, a.z, fmaf(s2z, bb.x, bb.z)));
    const int mbase = (uslice << 9) + (((gwin << 2) + q) << 1);
    if (p1s == best) bi = mbase + 1;
    if (p0s == best) bi = mbase;
  }

  rv[slice][pidx] = best;
  ri[slice][pidx] = bi;
  __syncthreads();

  if (slice == 0) {
    float bv = rv[0][pidx];
    int bidx = ri[0][pidx];
#pragma unroll
    for (int s = 1; s < 8; ++s) {
      const float v = rv[s][pidx];
      if (v > bv) { bv = v; bidx = ri[s][pidx]; }  // ascending slice: first max
    }
    // gather corr point (per-lane index -> vector loads)
    const int pr = bidx >> 1, h = bidx & 1;
    const float4 ca = PA_all[b * 2048 + pr];
    const float4 cb2 = PB_all[b * 2048 + pr];
    const float cx = h ? ca.y : ca.x;
    const float cy = h ? ca.w : ca.z;
    const float cz = h ? cb2.y : cb2.x;
    const float xx = fmaf(sx, sx, fmaf(sy, sy, sz * sz));
    float vals[16];
    vals[0] = bv - xx;          // val = max(2 s.d - yy) - xx
    vals[1] = sx;  vals[2] = sy;  vals[3] = sz;
    vals[4] = cx;  vals[5] = cy;  vals[6] = cz;
    vals[7]  = sx * cx; vals[8]  = sx * cy; vals[9]  = sx * cz;
    vals[10] = sy * cx; vals[11] = sy * cy; vals[12] = sy * cz;
    vals[13] = sz * cx; vals[14] = sz * cy; vals[15] = sz * cz;
#pragma unroll
    for (int k = 0; k < 16; ++k) {
      float v = vals[k];
#pragma unroll
      for (int off = 32; off >= 1; off >>= 1) v += __shfl_xor(v, off, 64);
      vals[k] = v;
    }
    if (pidx == 0) {
      float* Pp = ws + WS_PART + (it & 1) * 8192 + ((b << 6) + chunk) * 16;
#pragma unroll
      for (int k = 0; k < 16; ++k) Pp[k] = vals[k];
      ws[WS_PVAL + (it & 1) * 512 + (b << 6) + chunk] = vals[0];
    }
  }
}

// grid (16,8) x 256 thr (= dispatch 10): block-redundant solve of fit_9 from
// partials slot 1 (gated on done_8 in state slot 1), apply, write final src,
// emit partials for the final Kabsch.
__global__ void __launch_bounds__(256, 4) k_final(const float* __restrict__ srcInit,
                                                  float* __restrict__ ws,
                                                  float* __restrict__ out) {
  const int b = blockIdx.y;
  const int chunk = blockIdx.x;
  const int tid = threadIdx.x;
  const int n = (chunk << 8) + tid;
  __shared__ float red[4][15];
  __shared__ float s_RT[8][12];
  __shared__ float s_val[8];
  float* state = ws + WS_STATE;
  const float done8 = state[2 + 1];  // slot1.done (written by dispatch it=9)
  const int sbase = b * 3 * NPTS + n;
  float sx = ws[WS_SRC + sbase];
  float sy = ws[WS_SRC + sbase + NPTS];
  float sz = ws[WS_SRC + sbase + 2 * NPTS];
  if (done8 == 0.0f) {
    solve_head(ws + WS_PART + 8192, s_RT, s_val, tid);  // fit_9 from slot1
    __syncthreads();
    const float* RT = s_RT[b];
    const float nx = fmaf(RT[0], sx, fmaf(RT[1], sy, fmaf(RT[2], sz, RT[9])));
    const float ny = fmaf(RT[3], sx, fmaf(RT[4], sy, fmaf(RT[5], sz, RT[10])));
    const float nz = fmaf(RT[6], sx, fmaf(RT[7], sy, fmaf(RT[8], sz, RT[11])));
    sx = nx; sy = ny; sz = nz;
  }
  out[98304 + sbase] = sx;
  out[98304 + sbase + NPTS] = sy;
  out[98304 + sbase + 2 * NPTS] = sz;

  const float ax = srcInit[sbase];
  const float ay = srcInit[sbase + NPTS];
  const float az = srcInit[sbase + 2 * NPTS];
  float vals[15];
  vals[0] = ax; vals[1] = ay; vals[2] = az;
  vals[3] = sx; vals[4] = sy; vals[5] = sz;
  vals[6]  = ax * sx; vals[7]  = ax * sy; vals[8]  = ax * sz;
  vals[9]  = ay * sx; vals[10] = ay * sy; vals[11] = ay * sz;
  vals[12] = az * sx; vals[13] = az * sy; vals[14] = az * sz;
  const int w = tid >> 6, lane = tid & 63;
#pragma unroll
  for (int k = 0; k < 15; ++k) {
    float v = vals[k];
#pragma unroll
    for (int off = 32; off >= 1; off >>= 1) v += __shfl_xor(v, off, 64);
    vals[k] = v;
  }
  if (lane == 0) {
#pragma unroll
    for (int k = 0; k < 15; ++k) red[w][k] = vals[k];
  }
  __syncthreads();
  if (tid == 0) {
    float* FP = ws + WS_FPART + ((b << 4) + chunk) * 15;
#pragma unroll
    for (int k = 0; k < 15; ++k) FP[k] = red[0][k] + red[1][k] + red[2][k] + red[3][k];
  }
}

__global__ void __launch_bounds__(256) k_fsolve(float* __restrict__ ws, float* __restrict__ out) {
  const int t = threadIdx.x;
  const int b = t >> 5;
  const int j = t & 31;
  float acc[15];
  if (j < 16) {
    const float* F = ws + WS_FPART + ((b << 4) + j) * 15;
#pragma unroll
    for (int k = 0; k < 15; ++k) acc[k] = F[k];
  } else {
#pragma unroll
    for (int k = 0; k < 15; ++k) acc[k] = 0.0f;
  }
#pragma unroll
  for (int k = 0; k < 15; ++k) {
    float v = acc[k];
    v += __shfl_xor(v, 16, 64);
    v += __shfl_xor(v, 8, 64);
    v += __shfl_xor(v, 4, 64);
    v += __shfl_xor(v, 2, 64);
    v += __shfl_xor(v, 1, 64);
    acc[k] = v;
  }
  if (j == 0) {
    double Ss[3] = {acc[0], acc[1], acc[2]};
    double Sc[3] = {acc[3], acc[4], acc[5]};
    double Pm[9];
#pragma unroll
    for (int k = 0; k < 9; ++k) Pm[k] = acc[6 + k];
    double R[3][3], tr[3];
    kabsch3(Pm, Ss, Sc, R, tr);
#pragma unroll
    for (int i = 0; i < 3; ++i) {
#pragma unroll
      for (int jj = 0; jj < 3; ++jj) {
        out[196608 + b * 9 + i * 3 + jj] = (float)R[i][jj];       // rotation_ab
        out[196704 + b * 9 + i * 3 + jj] = (float)R[jj][i];       // rotation_ba = R^T
      }
      out[196680 + b * 3 + i] = (float)tr[i];                     // translation_ab
      out[196776 + b * 3 + i] =
          (float)(-(R[0][i] * tr[0] + R[1][i] * tr[1] + R[2][i] * tr[2]));  // -R^T t
    }
  }
}

extern "C" void kernel_launch(void* const* d_in, const int* in_sizes, int n_in,
                              void* d_out, int out_size, void* d_ws, size_t ws_size,
                              hipStream_t stream) {
  (void)in_sizes; (void)n_in; (void)out_size; (void)ws_size;
  const float* srcInit = (const float*)d_in[0];
  const float* dst = (const float*)d_in[1];
  float* out = (float*)d_out;
  float* ws = (float*)d_ws;
  const float4* PA_all = (const float4*)(ws + WS_PA);
  const float4* PB_all = (const float4*)(ws + WS_PB);

  k_prep<<<256, 256, 0, stream>>>(srcInit, dst, ws, out);
  for (int it = 0; it < 10; ++it)
    k_nn<<<dim3(64, 8), 512, 0, stream>>>(ws, PA_all, PB_all, it);
  k_final<<<dim3(16, 8), 256, 0, stream>>>(srcInit, ws, out);
  k_fsolve<<<1, 256, 0, stream>>>(ws, out);
}